// Round 1
// baseline (408.348 us; speedup 1.0000x reference)
//
#include <hip/hip_runtime.h>
#include <cstdint>
#include <cstddef>

#define DI __device__ __forceinline__

typedef __attribute__((ext_vector_type(8))) short short8;
typedef __attribute__((ext_vector_type(4))) float f32x4;

DI float bf2f(unsigned short u) {
  union { unsigned int i; float f; } c; c.i = ((unsigned int)u) << 16; return c.f;
}
DI unsigned short f2bf(float f) {
  union { float fl; unsigned int i; } c; c.fl = f;
  return (unsigned short)((c.i + 0x7FFFu + ((c.i >> 16) & 1u)) >> 16);
}

// ---- workspace layout (bytes) ----
static const size_t OFF_MB   = 256;                       // u32[128] mask bitwords
static const size_t OFF_RBF  = 1024;                      // f32[136] rel_bias
static const size_t OFF_PBF  = 2048;                      // f32[512] proj_b
static const size_t OFF_CNT  = 4096;                      // int[128] arrival counters
static const size_t OFF_AT   = 16384;                     // bf16 A_t[17][128][128]
static const size_t OFF_XQ   = OFF_AT + 557056;           // bf16 [2048][1024] (q|k)
static const size_t OFF_VT   = OFF_XQ + (size_t)4194304;  // bf16 [128bh][64d][128n]
static const size_t OFF_PW   = OFF_VT + (size_t)2097152;  // bf16 proj_w [512][512]
static const size_t OFF_PART = OFF_PW + (size_t)524288;   // f32 [1024][16][512] partials

// ---- phase1: blocks 0..127 prep (dispatch-first => starts early);
//              blocks 128..895 qkv GEMM (64x64 tile, ~3 blocks/CU) ----
__global__ __launch_bounds__(256) void k_phase1(
    const void* __restrict__ x, const void* __restrict__ qw,
    const void* __restrict__ kvw, const void* __restrict__ as,
    const unsigned char* __restrict__ mr, const void* __restrict__ rb,
    const void* __restrict__ pb, const void* __restrict__ pw,
    unsigned char* __restrict__ ws) {
  __shared__ unsigned short As[64 * 64];
  __shared__ unsigned short Bs[64 * 64];
  __shared__ int s_c0, s_3f, s_b1, s_odd;
  const int t = threadIdx.x;
  const int blk = blockIdx.x;

  if (t == 0) { s_c0 = 0; s_3f = 0; s_b1 = 0; s_odd = 0; }
  __syncthreads();
  // fmode self-detect (every block; 256B of x prefix, L2-broadcast after first)
  if (t < 128) {
    unsigned short u = ((const unsigned short*)x)[2 * t];
    int e = (u >> 7) & 0xFF;
    if (e >= 64 && e <= 150) atomicAdd(&s_c0, 1);
  }

  if (blk < 128) {
    // ============ prep: A_t repack via coalesced LDS transpose ============
    {
      int f3 = 0, b1 = 0, od = 0;
      for (int i = t; i < 2176; i += 256) {
        unsigned char bb = mr[i];
        if (bb == 0x3F) f3 = 1;
        if (bb) { if ((i & 3) == 1) b1 = 1; if (i & 3) od = 1; }
      }
      if (f3) atomicOr(&s_3f, 1);
      if (b1) atomicOr(&s_b1, 1);
      if (od) atomicOr(&s_odd, 1);
    }
    __syncthreads();
    const int fmode = (s_c0 >= 96) ? 0 : 1;
    const int mmode = s_3f ? (s_b1 ? 2 : 3) : (s_odd ? 0 : 1);
    unsigned short* At = (unsigned short*)(ws + OFF_AT);
    float* sL = (float*)As;                 // 1088 f32 = 4352 B staging
    // 128 mn-rows per block, 2 groups of 64: coalesced read -> LDS -> coalesced write
    for (int gi = 0; gi < 2; gi++) {
      int mn0 = blk * 128 + gi * 64;
      for (int j = t; j < 1088; j += 256)
        sL[j] = fmode ? ((const float*)as)[(size_t)mn0 * 17 + j]
                      : bf2f(((const unsigned short*)as)[(size_t)mn0 * 17 + j]);
      __syncthreads();
      for (int w = t; w < 1088; w += 256) {
        int r = w >> 6, jj = w & 63;
        At[(size_t)r * 16384 + mn0 + jj] = f2bf(sL[jj * 17 + r]);
      }
      __syncthreads();
    }
    // proj_w -> bf16 Pb (each prep block converts its 2048-element slice)
    {
      unsigned short* Pb = (unsigned short*)(ws + OFF_PW);
      const size_t pbase = (size_t)blk * 2048;
      if (fmode) {
        const float4* pwf = (const float4*)((const float*)pw + pbase);
        for (int j = t; j < 512; j += 256) {
          float4 v = pwf[j];
          ushort4 o;
          o.x = f2bf(v.x); o.y = f2bf(v.y); o.z = f2bf(v.z); o.w = f2bf(v.w);
          *(ushort4*)&Pb[pbase + (size_t)j * 4] = o;
        }
      } else {
        const ushort4* pwu = (const ushort4*)((const unsigned short*)pw + pbase);
        for (int j = t; j < 512; j += 256)
          *(ushort4*)&Pb[pbase + (size_t)j * 4] = pwu[j];
      }
    }
    if (blk == 0) {
      if (t == 0) { ((int*)ws)[0] = fmode; ((int*)ws)[1] = mmode; }
      if (t < 128) ((int*)(ws + OFF_CNT))[t] = 0;     // arrival counters
      unsigned int* MB = (unsigned int*)(ws + OFF_MB);
      float* RBf = (float*)(ws + OFF_RBF);
      float* PBf = (float*)(ws + OFF_PBF);
      if (t < 128) {
        unsigned int bits = 0;
        for (int r = 0; r < 17; r++) {
          int j = t * 17 + r, v;
          if (mmode == 0)      v = mr[j] != 0;
          else if (mmode == 1) v = ((const int*)mr)[j] != 0;
          else if (mmode == 2) v = ((const unsigned short*)mr)[j] != 0;
          else                 v = ((const float*)mr)[j] != 0.0f;
          bits |= (unsigned int)v << r;
        }
        MB[t] = bits;
      }
      for (int j = t; j < 136; j += 256)
        RBf[j] = fmode ? ((const float*)rb)[j] : bf2f(((const unsigned short*)rb)[j]);
      for (int j = t; j < 512; j += 256)
        PBf[j] = fmode ? ((const float*)pb)[j] : bf2f(((const unsigned short*)pb)[j]);
    }
  } else {
    // ============ qkv GEMM: C[2048,1536] = x @ [qw;kvw]^T, 64x64 tile ============
    __syncthreads();
    const int fmode = (s_c0 >= 96) ? 0 : 1;
    const int gb2 = blk - 128;
    const int bm = (gb2 & 31) * 64, bn = (gb2 >> 5) * 64;
    const int wv = t >> 6, l = t & 63, ln = l & 15, qd = l >> 4;
    f32x4 acc[4] = {};
    const int g_row8 = l >> 3;
    const int g_ck = (l & 7) ^ g_row8;
    const int s_row = t >> 2;
    const int s_cb = (t & 3) * 2;
    for (int k0 = 0; k0 < 512; k0 += 64) {
      if (!fmode) {
        const unsigned short* xb = (const unsigned short*)x;
#pragma unroll
        for (int jj = 0; jj < 2; jj++) {
          int j = 2 * wv + jj;
          const unsigned short* g = xb + (size_t)(bm + j * 8 + g_row8) * 512 + k0 + g_ck * 8;
          __builtin_amdgcn_global_load_lds(
              (const __attribute__((address_space(1))) unsigned int*)g,
              (__attribute__((address_space(3))) unsigned int*)(&As[j * 512 + l * 8]),
              16, 0, 0);
        }
#pragma unroll
        for (int jj = 0; jj < 2; jj++) {
          int j = 2 * wv + jj;
          int row = bn + j * 8 + g_row8;
          const unsigned short* base = (row < 512)
              ? (const unsigned short*)qw + (size_t)row * 512
              : (const unsigned short*)kvw + (size_t)(row - 512) * 512;
          const unsigned short* g = base + k0 + g_ck * 8;
          __builtin_amdgcn_global_load_lds(
              (const __attribute__((address_space(1))) unsigned int*)g,
              (__attribute__((address_space(3))) unsigned int*)(&Bs[j * 512 + l * 8]),
              16, 0, 0);
        }
      } else {
        const float* ga = (const float*)x + (size_t)(bm + s_row) * 512 + k0 + s_cb * 8;
        int brow = bn + s_row;
        const float* gb = ((brow < 512) ? (const float*)qw + (size_t)brow * 512
                                        : (const float*)kvw + (size_t)(brow - 512) * 512)
                          + k0 + s_cb * 8;
#pragma unroll
        for (int cc = 0; cc < 2; cc++) {
          unsigned short ta[8], tb[8];
#pragma unroll
          for (int u = 0; u < 8; u++) { ta[u] = f2bf(ga[cc * 8 + u]); tb[u] = f2bf(gb[cc * 8 + u]); }
          int pc = (s_cb + cc) ^ (s_row & 7);
          *(uint4*)&As[s_row * 64 + pc * 8] = *(const uint4*)ta;
          *(uint4*)&Bs[s_row * 64 + pc * 8] = *(const uint4*)tb;
        }
      }
      __syncthreads();
#pragma unroll
      for (int kk = 0; kk < 64; kk += 32) {
        int c = (kk >> 3) + qd;
        short8 af = *(const short8*)&As[(wv * 16 + ln) * 64 + ((c ^ (ln & 7)) * 8)];
#pragma unroll
        for (int tj = 0; tj < 4; tj++) {
          short8 bf = *(const short8*)&Bs[(tj * 16 + ln) * 64 + ((c ^ (ln & 7)) * 8)];
          acc[tj] = __builtin_amdgcn_mfma_f32_16x16x32_bf16(af, bf, acc[tj], 0, 0, 0);
        }
      }
      __syncthreads();
    }
    unsigned short* XQ = (unsigned short*)(ws + OFF_XQ);
    unsigned short* VT = (unsigned short*)(ws + OFF_VT);
#pragma unroll
    for (int tj = 0; tj < 4; tj++) {
      int col = bn + tj * 16 + ln;
      if (col >= 1024) {                       // V -> transposed, packed 8B store
        int c1 = col - 1024;
        int row0 = bm + wv * 16 + qd * 4;
        int bh = (row0 >> 7) * 8 + (c1 >> 6);
        ushort4 pk;
        pk.x = f2bf(acc[tj][0]); pk.y = f2bf(acc[tj][1]);
        pk.z = f2bf(acc[tj][2]); pk.w = f2bf(acc[tj][3]);
        *(ushort4*)&VT[((size_t)bh * 64 + (c1 & 63)) * 128 + (row0 & 127)] = pk;
      } else {
#pragma unroll
        for (int i = 0; i < 4; i++) {
          int row = bm + wv * 16 + qd * 4 + i;
          XQ[(size_t)row * 1024 + col] = f2bf(acc[tj][i]);
        }
      }
    }
  }
}

// ---- attention core + fused proj partial + last-arriver finalize ----
// 1024 blocks x 16 m-rows, ~29.2KB LDS. Each block computes its head's
// 16x512 proj partial; the 8th arriving block per (b,mq) row-group sums
// the 8 partials, adds bias, writes final output.
#define SST 132    // f32 per S row (pad); W bf16 overlays same rows (stride 264 u16)

__global__ __launch_bounds__(512) void k_attn_proj(
    const unsigned short* __restrict__ XQ, const unsigned short* __restrict__ VT,
    const unsigned short* __restrict__ AT, const unsigned int* __restrict__ MB,
    const float* __restrict__ RBf, const float* __restrict__ PBf,
    const unsigned short* __restrict__ Pb, float* __restrict__ PART,
    int* __restrict__ cnt, const int* __restrict__ flags,
    void* __restrict__ out) {
  __shared__ __align__(16) float Sf[16 * SST];          // 8448 B
  __shared__ __align__(16) unsigned short qs[16][72];   // 2304
  __shared__ __align__(16) unsigned short ks[128][72];  // 18432
  __shared__ int sLast;
  unsigned short* Wb = (unsigned short*)Sf;

  // 1024 blocks = (slot 0..127) x (xcd 0..7); m-eighth pinned to one XCD
  // -> per-L2 A_t hot set = 17*16*128*2 = 69 KB; all 8 h-contributors of a
  //    row-group land on the same XCD (same mq) -> L2-local partials.
  const int i0 = blockIdx.x;
  const int xcd = i0 & 7, slot = i0 >> 3;
  const int mq = xcd;                      // 0..7 (16 m-rows each)
  const int bhid = slot;                   // 0..127
  const int h = bhid & 7, b = bhid >> 3;
  const int bh = b * 8 + h;
  const int t = threadIdx.x;
  const int wv = t >> 6, l = t & 63, ln = l & 15, qd = l >> 4;

  // middle-section ids (also used for early A prefetch): 32 thr/row x 4 n-vals
  const int ml = t >> 5, q32 = t & 31, n0 = q32 * 4;
  const int m = mq * 16 + ml;
  const unsigned short* abase = AT + (size_t)m * 128 + n0;
  // early prefetch: first TWO A planes + mask bits issued before staging
  uint2 ca = *(const uint2*)abase;
  uint2 cb = *(const uint2*)(abase + 16384);
  const unsigned int mb = MB[m];

  // ---- staging: q(16x64)=128 uint4, k(128x64)=1024 uint4 ----
  for (int it = t; it < 1152; it += 512) {
    int row = it >> 3, ck = it & 7;
    if (row < 16) {
      const unsigned short* g = XQ + (size_t)(b * 128 + mq * 16 + row) * 1024 + h * 64 + ck * 8;
      *(uint4*)&qs[row][ck * 8] = *(const uint4*)g;
    } else {
      int nr = row - 16;
      const unsigned short* g = XQ + (size_t)(b * 128 + nr) * 1024 + 512 + h * 64 + ck * 8;
      *(uint4*)&ks[nr][ck * 8] = *(const uint4*)g;
    }
  }
  __syncthreads();

  // ---- S(16x128) = q @ k^T * scale : 8 waves, one 16x16 tile each ----
  {
    f32x4 accS = {};
#pragma unroll
    for (int kk = 0; kk < 64; kk += 32) {
      short8 af = *(const short8*)&qs[ln][kk + qd * 8];
      short8 bf = *(const short8*)&ks[wv * 16 + ln][kk + qd * 8];
      accS = __builtin_amdgcn_mfma_f32_16x16x32_bf16(af, bf, accS, 0, 0, 0);
    }
#pragma unroll
    for (int i = 0; i < 4; i++)
      Sf[(qd * 4 + i) * SST + wv * 16 + ln] = accS[i] * 0.125f;
  }
  __syncthreads();

  // ---- fused single-pass logits+softmax+W : 32 thr/row x 4 n-values ----
  // max-free softmax: logits O(10) << 88 (fp32 exp limit); dividing by the sum
  // afterwards is mathematically identical to ref softmax.
  {
    float sreg[4];
    {
      float4 s4 = *(const float4*)&Sf[ml * SST + n0];
      sreg[0] = s4.x; sreg[1] = s4.y; sreg[2] = s4.z; sreg[3] = s4.w;
    }
    float wacc[4];
#pragma unroll
    for (int j = 0; j < 4; j++) wacc[j] = 0.0f;
    float sum = 0.0f;
#pragma unroll
    for (int r = 0; r < 17; r++) {
      uint2 nn;
      if (r + 2 < 17) nn = *(const uint2*)(abase + (r + 2) * 16384);
      float av[4];
      const unsigned short* a8 = (const unsigned short*)&ca;
#pragma unroll
      for (int j = 0; j < 4; j++) av[j] = bf2f(a8[j]);
      float s = sreg[0] * av[0] + sreg[1] * av[1] + sreg[2] * av[2] + sreg[3] * av[3];
      s += __shfl_xor(s, 1);
      s += __shfl_xor(s, 2);
      s += __shfl_xor(s, 4);
      s += __shfl_xor(s, 8);
      s += __shfl_xor(s, 16);
      float e = ((mb >> r) & 1) ? 0.0f : __expf(s + RBf[h * 17 + r]);
      sum += e;
#pragma unroll
      for (int j = 0; j < 4; j++) wacc[j] += e * av[j];
      ca = cb; cb = nn;
    }
    const float inv = 1.0f / sum;
    unsigned short pk[4];
#pragma unroll
    for (int j = 0; j < 4; j++) pk[j] = f2bf(wacc[j] * inv);
    // W overlays same-row S bytes; the row's 32 threads live in one wave
    // (lanes 0-31 or 32-63) and all S reads precede these writes in program order
    *(uint2*)&Wb[ml * 264 + n0] = *(const uint2*)&pk[0];
  }
  __syncthreads();

  // ---- out(16x64) = W(16x128) @ v(128x64) : waves 0-3, one d-tile each ----
  // result goes to LDS (attL, overlays dead ks) instead of global ATTO.
  unsigned short* attL = &ks[0][0];    // [16][72] bf16, 16B-aligned rows (144B)
  if (wv < 4) {
    f32x4 accO = {};
    const int d = wv * 16 + ln;
    const unsigned short* vrow = VT + ((size_t)bh * 64 + d) * 128;
#pragma unroll
    for (int kk = 0; kk < 128; kk += 32) {
      short8 af = *(const short8*)&Wb[ln * 264 + kk + qd * 8];
      short8 bf = *(const short8*)(vrow + kk + qd * 8);
      accO = __builtin_amdgcn_mfma_f32_16x16x32_bf16(af, bf, accO, 0, 0, 0);
    }
#pragma unroll
    for (int i = 0; i < 4; i++)
      attL[(qd * 4 + i) * 72 + d] = f2bf(accO[i]);
  }
  __syncthreads();

  // ---- fused proj partial: out16x512 += att(16x64) @ proj_w[:, h*64:+64]^T ----
  // all 8 waves; wave wv owns output cols wv*64..wv*64+63 (4 c-tiles).
  {
    short8 afk0 = *(const short8*)&attL[ln * 72 + qd * 8];
    short8 afk1 = *(const short8*)&attL[ln * 72 + 32 + qd * 8];
    float* part = PART + (((size_t)(b * 8 + mq) * 8 + h) << 13);   // *8192
#pragma unroll
    for (int tj = 0; tj < 4; tj++) {
      const unsigned short* prow = Pb + (size_t)(wv * 64 + tj * 16 + ln) * 512 + h * 64;
      short8 bf0 = *(const short8*)(prow + qd * 8);
      short8 bf1 = *(const short8*)(prow + 32 + qd * 8);
      f32x4 p = {};
      p = __builtin_amdgcn_mfma_f32_16x16x32_bf16(afk0, bf0, p, 0, 0, 0);
      p = __builtin_amdgcn_mfma_f32_16x16x32_bf16(afk1, bf1, p, 0, 0, 0);
#pragma unroll
      for (int i = 0; i < 4; i++)
        part[(qd * 4 + i) * 512 + wv * 64 + tj * 16 + ln] = p[i];
    }
  }

  // ---- arrival counter: 8 blocks (h=0..7) per (b,mq) row-group ----
  __threadfence();          // release: partials visible device-wide
  __syncthreads();
  if (t == 0) sLast = (atomicAdd(&cnt[b * 8 + mq], 1) == 7) ? 1 : 0;
  __syncthreads();
  if (!sLast) return;

  // ---- finalize (last arriver): sum 8 partials + bias -> output ----
  __threadfence();          // acquire: see other blocks' partials
  {
    const int fmode = flags[0];
    const float* p0 = PART + ((size_t)(b * 8 + mq) << 16);   // *65536
    const int row = t >> 5, c0 = (t & 31) * 16;
    f32x4 s[4];
#pragma unroll
    for (int j = 0; j < 4; j++) s[j] = *(const f32x4*)&PBf[c0 + j * 4];
#pragma unroll
    for (int hh = 0; hh < 8; hh++) {
#pragma unroll
      for (int j = 0; j < 4; j++)
        s[j] += *(const f32x4*)&p0[(size_t)hh * 8192 + row * 512 + c0 + j * 4];
    }
    const size_t grow = (size_t)(b * 128 + mq * 16 + row) * 512 + c0;
    if (fmode) {
      float* of = (float*)out;
#pragma unroll
      for (int j = 0; j < 4; j++) *(f32x4*)&of[grow + j * 4] = s[j];
    } else {
      unsigned short pk[16];
#pragma unroll
      for (int j = 0; j < 4; j++)
#pragma unroll
        for (int i = 0; i < 4; i++) pk[j * 4 + i] = f2bf(s[j][i]);
      unsigned short* ou = (unsigned short*)out;
      *(uint4*)&ou[grow] = *(const uint4*)&pk[0];
      *(uint4*)&ou[grow + 8] = *(const uint4*)&pk[8];
    }
  }
}

extern "C" void kernel_launch(void* const* d_in, const int* in_sizes, int n_in,
                              void* d_out, int out_size, void* d_ws, size_t ws_size,
                              hipStream_t stream) {
  unsigned char* ws = (unsigned char*)d_ws;
  // 0:x 1:assignment 2:mask 3:q_w 4:kv_w 5:rel_bias 6:proj_w 7:proj_b
  k_phase1<<<896, 256, 0, stream>>>(d_in[0], d_in[3], d_in[4], d_in[1],
                                    (const unsigned char*)d_in[2],
                                    d_in[5], d_in[7], d_in[6], ws);
  k_attn_proj<<<1024, 512, 0, stream>>>(
      (const unsigned short*)(ws + OFF_XQ),
      (const unsigned short*)(ws + OFF_VT),
      (const unsigned short*)(ws + OFF_AT),
      (const unsigned int*)(ws + OFF_MB),
      (const float*)(ws + OFF_RBF),
      (const float*)(ws + OFF_PBF),
      (const unsigned short*)(ws + OFF_PW),
      (float*)(ws + OFF_PART),
      (int*)(ws + OFF_CNT),
      (const int*)ws, d_out);
}

// Round 2
// 115.267 us; speedup vs baseline: 3.5426x; 3.5426x over previous
//
#include <hip/hip_runtime.h>
#include <cstdint>
#include <cstddef>

#define DI __device__ __forceinline__

typedef __attribute__((ext_vector_type(8))) short short8;
typedef __attribute__((ext_vector_type(4))) float f32x4;

DI float bf2f(unsigned short u) {
  union { unsigned int i; float f; } c; c.i = ((unsigned int)u) << 16; return c.f;
}
DI unsigned short f2bf(float f) {
  union { float fl; unsigned int i; } c; c.fl = f;
  return (unsigned short)((c.i + 0x7FFFu + ((c.i >> 16) & 1u)) >> 16);
}

// ---- workspace layout (bytes) ----
static const size_t OFF_MB   = 256;                       // u32[128] mask bitwords
static const size_t OFF_RBF  = 1024;                      // f32[136] rel_bias
static const size_t OFF_PBF  = 2048;                      // f32[512] proj_b
static const size_t OFF_AT   = 16384;                     // bf16 A_t[17][128][128]
static const size_t OFF_XQ   = OFF_AT + 557056;           // bf16 [2048][1024] (q|k)
static const size_t OFF_VT   = OFF_XQ + (size_t)4194304;  // bf16 [128bh][64d][128n]
static const size_t OFF_ATTO = OFF_VT + (size_t)2097152;  // bf16 [2048][512] (bf16 path only)
static const size_t OFF_PW   = OFF_ATTO + (size_t)2097152; // bf16 proj_w [512][512]

// ---- phase1: blocks 0..127 prep (dispatch-first => starts early);
//              blocks 128..895 qkv GEMM (64x64 tile, ~3 blocks/CU) ----
__global__ __launch_bounds__(256) void k_phase1(
    const void* __restrict__ x, const void* __restrict__ qw,
    const void* __restrict__ kvw, const void* __restrict__ as,
    const unsigned char* __restrict__ mr, const void* __restrict__ rb,
    const void* __restrict__ pb, const void* __restrict__ pw,
    unsigned char* __restrict__ ws, void* __restrict__ outp) {
  __shared__ unsigned short As[64 * 64];
  __shared__ unsigned short Bs[64 * 64];
  __shared__ int s_c0, s_3f, s_b1, s_odd;
  const int t = threadIdx.x;
  const int blk = blockIdx.x;

  if (t == 0) { s_c0 = 0; s_3f = 0; s_b1 = 0; s_odd = 0; }
  __syncthreads();
  // fmode self-detect (every block; 256B of x prefix, L2-broadcast after first)
  if (t < 128) {
    unsigned short u = ((const unsigned short*)x)[2 * t];
    int e = (u >> 7) & 0xFF;
    if (e >= 64 && e <= 150) atomicAdd(&s_c0, 1);
  }

  if (blk < 128) {
    // ============ prep: A_t repack via coalesced LDS transpose ============
    {
      int f3 = 0, b1 = 0, od = 0;
      for (int i = t; i < 2176; i += 256) {
        unsigned char bb = mr[i];
        if (bb == 0x3F) f3 = 1;
        if (bb) { if ((i & 3) == 1) b1 = 1; if (i & 3) od = 1; }
      }
      if (f3) atomicOr(&s_3f, 1);
      if (b1) atomicOr(&s_b1, 1);
      if (od) atomicOr(&s_odd, 1);
    }
    __syncthreads();
    const int fmode = (s_c0 >= 96) ? 0 : 1;
    const int mmode = s_3f ? (s_b1 ? 2 : 3) : (s_odd ? 0 : 1);
    unsigned short* At = (unsigned short*)(ws + OFF_AT);
    float* sL = (float*)As;                 // 1088 f32 = 4352 B staging
    // 128 mn-rows per block, 2 groups of 64: coalesced read -> LDS -> coalesced write
    for (int gi = 0; gi < 2; gi++) {
      int mn0 = blk * 128 + gi * 64;
      for (int j = t; j < 1088; j += 256)
        sL[j] = fmode ? ((const float*)as)[(size_t)mn0 * 17 + j]
                      : bf2f(((const unsigned short*)as)[(size_t)mn0 * 17 + j]);
      __syncthreads();
      for (int w = t; w < 1088; w += 256) {
        int r = w >> 6, jj = w & 63;
        At[(size_t)r * 16384 + mn0 + jj] = f2bf(sL[jj * 17 + r]);
      }
      __syncthreads();
    }
    // proj_w -> bf16 Pb (each prep block converts its 2048-element slice)
    {
      unsigned short* Pb = (unsigned short*)(ws + OFF_PW);
      const size_t pbase = (size_t)blk * 2048;
      if (fmode) {
        const float4* pwf = (const float4*)((const float*)pw + pbase);
        for (int j = t; j < 512; j += 256) {
          float4 v = pwf[j];
          ushort4 o;
          o.x = f2bf(v.x); o.y = f2bf(v.y); o.z = f2bf(v.z); o.w = f2bf(v.w);
          *(ushort4*)&Pb[pbase + (size_t)j * 4] = o;
        }
      } else {
        const ushort4* pwu = (const ushort4*)((const unsigned short*)pw + pbase);
        for (int j = t; j < 512; j += 256)
          *(ushort4*)&Pb[pbase + (size_t)j * 4] = pwu[j];
      }
    }
    // f32 mode: init out rows with bias (fused-atomic proj adds into it)
    if (fmode) {
      float* of = (float*)outp + (size_t)blk * 16 * 512;
      const float* pbf = (const float*)pb;
      for (int j = t; j < 8192; j += 256) of[j] = pbf[j & 511];
    }
    if (blk == 0) {
      if (t == 0) { ((int*)ws)[0] = fmode; ((int*)ws)[1] = mmode; }
      unsigned int* MB = (unsigned int*)(ws + OFF_MB);
      float* RBf = (float*)(ws + OFF_RBF);
      float* PBf = (float*)(ws + OFF_PBF);
      if (t < 128) {
        unsigned int bits = 0;
        for (int r = 0; r < 17; r++) {
          int j = t * 17 + r, v;
          if (mmode == 0)      v = mr[j] != 0;
          else if (mmode == 1) v = ((const int*)mr)[j] != 0;
          else if (mmode == 2) v = ((const unsigned short*)mr)[j] != 0;
          else                 v = ((const float*)mr)[j] != 0.0f;
          bits |= (unsigned int)v << r;
        }
        MB[t] = bits;
      }
      for (int j = t; j < 136; j += 256)
        RBf[j] = fmode ? ((const float*)rb)[j] : bf2f(((const unsigned short*)rb)[j]);
      for (int j = t; j < 512; j += 256)
        PBf[j] = fmode ? ((const float*)pb)[j] : bf2f(((const unsigned short*)pb)[j]);
    }
  } else {
    // ============ qkv GEMM: C[2048,1536] = x @ [qw;kvw]^T, 64x64 tile ============
    __syncthreads();
    const int fmode = (s_c0 >= 96) ? 0 : 1;
    const int gb2 = blk - 128;
    const int bm = (gb2 & 31) * 64, bn = (gb2 >> 5) * 64;
    const int wv = t >> 6, l = t & 63, ln = l & 15, qd = l >> 4;
    f32x4 acc[4] = {};
    const int g_row8 = l >> 3;
    const int g_ck = (l & 7) ^ g_row8;
    const int s_row = t >> 2;
    const int s_cb = (t & 3) * 2;
    for (int k0 = 0; k0 < 512; k0 += 64) {
      if (!fmode) {
        const unsigned short* xb = (const unsigned short*)x;
#pragma unroll
        for (int jj = 0; jj < 2; jj++) {
          int j = 2 * wv + jj;
          const unsigned short* g = xb + (size_t)(bm + j * 8 + g_row8) * 512 + k0 + g_ck * 8;
          __builtin_amdgcn_global_load_lds(
              (const __attribute__((address_space(1))) unsigned int*)g,
              (__attribute__((address_space(3))) unsigned int*)(&As[j * 512 + l * 8]),
              16, 0, 0);
        }
#pragma unroll
        for (int jj = 0; jj < 2; jj++) {
          int j = 2 * wv + jj;
          int row = bn + j * 8 + g_row8;
          const unsigned short* base = (row < 512)
              ? (const unsigned short*)qw + (size_t)row * 512
              : (const unsigned short*)kvw + (size_t)(row - 512) * 512;
          const unsigned short* g = base + k0 + g_ck * 8;
          __builtin_amdgcn_global_load_lds(
              (const __attribute__((address_space(1))) unsigned int*)g,
              (__attribute__((address_space(3))) unsigned int*)(&Bs[j * 512 + l * 8]),
              16, 0, 0);
        }
      } else {
        const float* ga = (const float*)x + (size_t)(bm + s_row) * 512 + k0 + s_cb * 8;
        int brow = bn + s_row;
        const float* gb = ((brow < 512) ? (const float*)qw + (size_t)brow * 512
                                        : (const float*)kvw + (size_t)(brow - 512) * 512)
                          + k0 + s_cb * 8;
#pragma unroll
        for (int cc = 0; cc < 2; cc++) {
          unsigned short ta[8], tb[8];
#pragma unroll
          for (int u = 0; u < 8; u++) { ta[u] = f2bf(ga[cc * 8 + u]); tb[u] = f2bf(gb[cc * 8 + u]); }
          int pc = (s_cb + cc) ^ (s_row & 7);
          *(uint4*)&As[s_row * 64 + pc * 8] = *(const uint4*)ta;
          *(uint4*)&Bs[s_row * 64 + pc * 8] = *(const uint4*)tb;
        }
      }
      __syncthreads();
#pragma unroll
      for (int kk = 0; kk < 64; kk += 32) {
        int c = (kk >> 3) + qd;
        short8 af = *(const short8*)&As[(wv * 16 + ln) * 64 + ((c ^ (ln & 7)) * 8)];
#pragma unroll
        for (int tj = 0; tj < 4; tj++) {
          short8 bf = *(const short8*)&Bs[(tj * 16 + ln) * 64 + ((c ^ (ln & 7)) * 8)];
          acc[tj] = __builtin_amdgcn_mfma_f32_16x16x32_bf16(af, bf, acc[tj], 0, 0, 0);
        }
      }
      __syncthreads();
    }
    unsigned short* XQ = (unsigned short*)(ws + OFF_XQ);
    unsigned short* VT = (unsigned short*)(ws + OFF_VT);
#pragma unroll
    for (int tj = 0; tj < 4; tj++) {
      int col = bn + tj * 16 + ln;
      if (col >= 1024) {                       // V -> transposed, packed 8B store
        int c1 = col - 1024;
        int row0 = bm + wv * 16 + qd * 4;
        int bh = (row0 >> 7) * 8 + (c1 >> 6);
        ushort4 pk;
        pk.x = f2bf(acc[tj][0]); pk.y = f2bf(acc[tj][1]);
        pk.z = f2bf(acc[tj][2]); pk.w = f2bf(acc[tj][3]);
        *(ushort4*)&VT[((size_t)bh * 64 + (c1 & 63)) * 128 + (row0 & 127)] = pk;
      } else {
#pragma unroll
        for (int i = 0; i < 4; i++) {
          int row = bm + wv * 16 + qd * 4 + i;
          XQ[(size_t)row * 1024 + col] = f2bf(acc[tj][i]);
        }
      }
    }
  }
}

// ---- attention core: 1024 blocks x 16 m-rows, ~29.2KB LDS -> 4 blocks/CU ----
// FUSED=1 (f32 harness): proj partial in-block + unsafeAtomicAdd into out
//   (no fences: global_atomic_add_f32 is coherent at the L2/fabric point).
// FUSED=0 (bf16 harness): round-0 path, writes bf16 ATTO; k_proj follows.
#define SST 132    // f32 per S row (pad); W bf16 overlays same rows (stride 264 u16)

template <int FUSED>
__global__ __launch_bounds__(512) void k_attn(
    const unsigned short* __restrict__ XQ, const unsigned short* __restrict__ VT,
    const unsigned short* __restrict__ AT, const unsigned int* __restrict__ MB,
    const float* __restrict__ RBf, const unsigned short* __restrict__ Pb,
    unsigned short* __restrict__ ATTO, float* __restrict__ out) {
  __shared__ __align__(16) float Sf[16 * SST];          // 8448 B
  __shared__ __align__(16) unsigned short qs[16][72];   // 2304
  __shared__ __align__(16) unsigned short ks[128][72];  // 18432
  unsigned short* Wb = (unsigned short*)Sf;

  // 1024 blocks = (slot 0..127) x (xcd 0..7); m-eighth pinned to one XCD
  // -> per-L2 A_t hot set = 17*16*128*2 = 69 KB.
  const int i0 = blockIdx.x;
  const int xcd = i0 & 7, slot = i0 >> 3;
  const int mq = xcd;                      // 0..7 (16 m-rows each)
  const int bhid = slot;                   // 0..127
  const int h = bhid & 7, b = bhid >> 3;
  const int bh = b * 8 + h;
  const int t = threadIdx.x;
  const int wv = t >> 6, l = t & 63, ln = l & 15, qd = l >> 4;

  // middle-section ids (also used for early A prefetch): 32 thr/row x 4 n-vals
  const int ml = t >> 5, q32 = t & 31, n0 = q32 * 4;
  const int m = mq * 16 + ml;
  const unsigned short* abase = AT + (size_t)m * 128 + n0;
  // early prefetch: first TWO A planes + mask bits issued before staging
  uint2 ca = *(const uint2*)abase;
  uint2 cb = *(const uint2*)(abase + 16384);
  const unsigned int mb = MB[m];

  // ---- staging: q(16x64)=128 uint4, k(128x64)=1024 uint4 ----
  for (int it = t; it < 1152; it += 512) {
    int row = it >> 3, ck = it & 7;
    if (row < 16) {
      const unsigned short* g = XQ + (size_t)(b * 128 + mq * 16 + row) * 1024 + h * 64 + ck * 8;
      *(uint4*)&qs[row][ck * 8] = *(const uint4*)g;
    } else {
      int nr = row - 16;
      const unsigned short* g = XQ + (size_t)(b * 128 + nr) * 1024 + 512 + h * 64 + ck * 8;
      *(uint4*)&ks[nr][ck * 8] = *(const uint4*)g;
    }
  }
  __syncthreads();

  // ---- S(16x128) = q @ k^T * scale : 8 waves, one 16x16 tile each ----
  {
    f32x4 accS = {};
#pragma unroll
    for (int kk = 0; kk < 64; kk += 32) {
      short8 af = *(const short8*)&qs[ln][kk + qd * 8];
      short8 bf = *(const short8*)&ks[wv * 16 + ln][kk + qd * 8];
      accS = __builtin_amdgcn_mfma_f32_16x16x32_bf16(af, bf, accS, 0, 0, 0);
    }
#pragma unroll
    for (int i = 0; i < 4; i++)
      Sf[(qd * 4 + i) * SST + wv * 16 + ln] = accS[i] * 0.125f;
  }
  __syncthreads();

  // ---- fused single-pass logits+softmax+W : 32 thr/row x 4 n-values ----
  // max-free softmax: logits O(10) << 88 (fp32 exp limit); dividing by the sum
  // afterwards is mathematically identical to ref softmax.
  {
    float sreg[4];
    {
      float4 s4 = *(const float4*)&Sf[ml * SST + n0];
      sreg[0] = s4.x; sreg[1] = s4.y; sreg[2] = s4.z; sreg[3] = s4.w;
    }
    float wacc[4];
#pragma unroll
    for (int j = 0; j < 4; j++) wacc[j] = 0.0f;
    float sum = 0.0f;
#pragma unroll
    for (int r = 0; r < 17; r++) {
      uint2 nn;
      if (r + 2 < 17) nn = *(const uint2*)(abase + (r + 2) * 16384);
      float av[4];
      const unsigned short* a8 = (const unsigned short*)&ca;
#pragma unroll
      for (int j = 0; j < 4; j++) av[j] = bf2f(a8[j]);
      float s = sreg[0] * av[0] + sreg[1] * av[1] + sreg[2] * av[2] + sreg[3] * av[3];
      s += __shfl_xor(s, 1);
      s += __shfl_xor(s, 2);
      s += __shfl_xor(s, 4);
      s += __shfl_xor(s, 8);
      s += __shfl_xor(s, 16);
      float e = ((mb >> r) & 1) ? 0.0f : __expf(s + RBf[h * 17 + r]);
      sum += e;
#pragma unroll
      for (int j = 0; j < 4; j++) wacc[j] += e * av[j];
      ca = cb; cb = nn;
    }
    const float inv = 1.0f / sum;
    unsigned short pk[4];
#pragma unroll
    for (int j = 0; j < 4; j++) pk[j] = f2bf(wacc[j] * inv);
    // W overlays same-row S bytes; the row's 32 threads live in one wave
    // (lanes 0-31 or 32-63) and all S reads precede these writes in program order
    *(uint2*)&Wb[ml * 264 + n0] = *(const uint2*)&pk[0];
  }
  __syncthreads();

  if constexpr (!FUSED) {
    // ---- out(16x64) = W(16x128) @ v(128x64) -> global ATTO (bf16 path) ----
    if (wv < 4) {
      f32x4 accO = {};
      const int d = wv * 16 + ln;
      const unsigned short* vrow = VT + ((size_t)bh * 64 + d) * 128;
#pragma unroll
      for (int kk = 0; kk < 128; kk += 32) {
        short8 af = *(const short8*)&Wb[ln * 264 + kk + qd * 8];
        short8 bf = *(const short8*)(vrow + kk + qd * 8);
        accO = __builtin_amdgcn_mfma_f32_16x16x32_bf16(af, bf, accO, 0, 0, 0);
      }
#pragma unroll
      for (int i = 0; i < 4; i++) {
        int row = b * 128 + mq * 16 + qd * 4 + i;
        ATTO[(size_t)row * 512 + h * 64 + (wv * 16 + ln)] = f2bf(accO[i]);
      }
    }
  } else {
    // ---- out(16x64) = W @ v -> LDS attL (overlays dead ks) ----
    unsigned short* attL = &ks[0][0];    // [16][72] bf16, 16B-aligned rows
    if (wv < 4) {
      f32x4 accO = {};
      const int d = wv * 16 + ln;
      const unsigned short* vrow = VT + ((size_t)bh * 64 + d) * 128;
#pragma unroll
      for (int kk = 0; kk < 128; kk += 32) {
        short8 af = *(const short8*)&Wb[ln * 264 + kk + qd * 8];
        short8 bf = *(const short8*)(vrow + kk + qd * 8);
        accO = __builtin_amdgcn_mfma_f32_16x16x32_bf16(af, bf, accO, 0, 0, 0);
      }
#pragma unroll
      for (int i = 0; i < 4; i++)
        attL[(qd * 4 + i) * 72 + d] = f2bf(accO[i]);
    }
    __syncthreads();

    // ---- fused proj partial: att(16x64) @ proj_w[:, h*64:+64]^T, all 8 waves;
    //      wave wv owns output cols wv*64..+63; atomic-add into bias-inited out.
    short8 afk0 = *(const short8*)&attL[ln * 72 + qd * 8];
    short8 afk1 = *(const short8*)&attL[ln * 72 + 32 + qd * 8];
    float* orow = out + (size_t)(b * 128 + mq * 16) * 512;
#pragma unroll
    for (int tj = 0; tj < 4; tj++) {
      const unsigned short* prow = Pb + (size_t)(wv * 64 + tj * 16 + ln) * 512 + h * 64;
      short8 bf0 = *(const short8*)(prow + qd * 8);
      short8 bf1 = *(const short8*)(prow + 32 + qd * 8);
      f32x4 p = {};
      p = __builtin_amdgcn_mfma_f32_16x16x32_bf16(afk0, bf0, p, 0, 0, 0);
      p = __builtin_amdgcn_mfma_f32_16x16x32_bf16(afk1, bf1, p, 0, 0, 0);
#pragma unroll
      for (int i = 0; i < 4; i++)
        unsafeAtomicAdd(&orow[(size_t)(qd * 4 + i) * 512 + wv * 64 + tj * 16 + ln], p[i]);
    }
  }
}

// ---- proj GEMM (bf16 path only): 64x32 tiles, 512 blocks ----
__global__ __launch_bounds__(256) void k_proj(
    const unsigned short* __restrict__ A,   // ATTO bf16 [2048][512]
    const void* __restrict__ Bw,            // proj_w raw
    const float* __restrict__ biasf,
    const int* __restrict__ flags, void* __restrict__ C) {
  __shared__ unsigned short As[64 * 64];
  __shared__ unsigned short Bs[32 * 64];
  const int fmode = flags[0];
  const int bm = blockIdx.x * 64, bn = blockIdx.y * 32;
  const int t = threadIdx.x, wv = t >> 6, l = t & 63, ln = l & 15, qd = l >> 4;
  f32x4 acc[2] = {};
  const int g_row8 = l >> 3;
  const int g_ck = (l & 7) ^ g_row8;
  for (int k0 = 0; k0 < 512; k0 += 64) {
#pragma unroll
    for (int jj = 0; jj < 2; jj++) {
      int j = 2 * wv + jj;
      const unsigned short* g = A + (size_t)(bm + j * 8 + g_row8) * 512 + k0 + g_ck * 8;
      __builtin_amdgcn_global_load_lds(
          (const __attribute__((address_space(1))) unsigned int*)g,
          (__attribute__((address_space(3))) unsigned int*)(&As[j * 512 + l * 8]),
          16, 0, 0);
    }
    if (!fmode) {
      int row = bn + wv * 8 + g_row8;
      const unsigned short* g = (const unsigned short*)Bw + (size_t)row * 512 + k0 + g_ck * 8;
      __builtin_amdgcn_global_load_lds(
          (const __attribute__((address_space(1))) unsigned int*)g,
          (__attribute__((address_space(3))) unsigned int*)(&Bs[wv * 512 + l * 8]),
          16, 0, 0);
    } else {
      int row = t >> 3, cb = t & 7;     // 32 rows x 8 chunks
      const float* g = (const float*)Bw + (size_t)(bn + row) * 512 + k0 + cb * 8;
      unsigned short tb[8];
#pragma unroll
      for (int u = 0; u < 8; u++) tb[u] = f2bf(g[u]);
      int pc = cb ^ (row & 7);
      *(uint4*)&Bs[row * 64 + pc * 8] = *(const uint4*)tb;
    }
    __syncthreads();
#pragma unroll
    for (int kk = 0; kk < 64; kk += 32) {
      int c = (kk >> 3) + qd;
      short8 af = *(const short8*)&As[(wv * 16 + ln) * 64 + ((c ^ (ln & 7)) * 8)];
#pragma unroll
      for (int tj = 0; tj < 2; tj++) {
        short8 bf = *(const short8*)&Bs[(tj * 16 + ln) * 64 + ((c ^ (ln & 7)) * 8)];
        acc[tj] = __builtin_amdgcn_mfma_f32_16x16x32_bf16(af, bf, acc[tj], 0, 0, 0);
      }
    }
    __syncthreads();
  }
#pragma unroll
  for (int tj = 0; tj < 2; tj++) {
    int col = bn + tj * 16 + ln;
    float bv = biasf[col];
#pragma unroll
    for (int i = 0; i < 4; i++) {
      int row = bm + wv * 16 + qd * 4 + i;
      float v = acc[tj][i] + bv;
      if (fmode) ((float*)C)[(size_t)row * 512 + col] = v;
      else       ((unsigned short*)C)[(size_t)row * 512 + col] = f2bf(v);
    }
  }
}

extern "C" void kernel_launch(void* const* d_in, const int* in_sizes, int n_in,
                              void* d_out, int out_size, void* d_ws, size_t ws_size,
                              hipStream_t stream) {
  unsigned char* ws = (unsigned char*)d_ws;
  // 0:x 1:assignment 2:mask 3:q_w 4:kv_w 5:rel_bias 6:proj_w 7:proj_b
  // dtype dispatch at capture time: x f32 = 16*128*512*4 bytes
  const bool f32in = (in_sizes[0] >= 16 * 128 * 512 * 4);
  k_phase1<<<896, 256, 0, stream>>>(d_in[0], d_in[3], d_in[4], d_in[1],
                                    (const unsigned char*)d_in[2],
                                    d_in[5], d_in[7], d_in[6], ws, d_out);
  if (f32in) {
    k_attn<1><<<1024, 512, 0, stream>>>(
        (const unsigned short*)(ws + OFF_XQ),
        (const unsigned short*)(ws + OFF_VT),
        (const unsigned short*)(ws + OFF_AT),
        (const unsigned int*)(ws + OFF_MB),
        (const float*)(ws + OFF_RBF),
        (const unsigned short*)(ws + OFF_PW),
        nullptr, (float*)d_out);
  } else {
    k_attn<0><<<1024, 512, 0, stream>>>(
        (const unsigned short*)(ws + OFF_XQ),
        (const unsigned short*)(ws + OFF_VT),
        (const unsigned short*)(ws + OFF_AT),
        (const unsigned int*)(ws + OFF_MB),
        (const float*)(ws + OFF_RBF),
        nullptr, (unsigned short*)(ws + OFF_ATTO), nullptr);
    k_proj<<<dim3(32, 16), 256, 0, stream>>>(
        (const unsigned short*)(ws + OFF_ATTO), d_in[6],
        (const float*)(ws + OFF_PBF), (const int*)ws, d_out);
  }
}

// Round 3
// 114.779 us; speedup vs baseline: 3.5577x; 1.0043x over previous
//
#include <hip/hip_runtime.h>
#include <cstdint>
#include <cstddef>

#define DI __device__ __forceinline__

typedef __attribute__((ext_vector_type(8))) short short8;
typedef __attribute__((ext_vector_type(4))) float f32x4;

DI float bf2f(unsigned short u) {
  union { unsigned int i; float f; } c; c.i = ((unsigned int)u) << 16; return c.f;
}
DI unsigned short f2bf(float f) {
  union { float fl; unsigned int i; } c; c.fl = f;
  return (unsigned short)((c.i + 0x7FFFu + ((c.i >> 16) & 1u)) >> 16);
}

// DPP lane-shuffled copy (quad_perm / row_ror): full-rate VALU, no LDS pipe.
template <int CTRL>
DI float dppf(float v) {
  return __int_as_float(__builtin_amdgcn_update_dpp(
      0, __float_as_int(v), CTRL, 0xF, 0xF, true));
}

// ---- workspace layout (bytes) ----
static const size_t OFF_MB   = 256;                       // u32[128] mask bitwords
static const size_t OFF_RBF  = 1024;                      // f32[136] rel_bias
static const size_t OFF_PBF  = 2048;                      // f32[512] proj_b
static const size_t OFF_AT   = 16384;                     // bf16 A_t[17][128][128]
static const size_t OFF_XQ   = OFF_AT + 557056;           // bf16 [2048][1024] (q|k)
static const size_t OFF_VT   = OFF_XQ + (size_t)4194304;  // bf16 [128bh][64d][128n]
static const size_t OFF_ATTO = OFF_VT + (size_t)2097152;  // bf16 [2048][512] (bf16 path only)
static const size_t OFF_PW   = OFF_ATTO + (size_t)2097152; // bf16 proj_w [512][512]

// ---- phase1: blocks 0..127 prep (dispatch-first => starts early);
//              blocks 128..895 qkv GEMM (64x64 tile, ~3 blocks/CU) ----
__global__ __launch_bounds__(256) void k_phase1(
    const void* __restrict__ x, const void* __restrict__ qw,
    const void* __restrict__ kvw, const void* __restrict__ as,
    const unsigned char* __restrict__ mr, const void* __restrict__ rb,
    const void* __restrict__ pb, const void* __restrict__ pw,
    unsigned char* __restrict__ ws, void* __restrict__ outp) {
  __shared__ unsigned short As[64 * 64];
  __shared__ unsigned short Bs[64 * 64];
  __shared__ int s_c0, s_3f, s_b1, s_odd;
  const int t = threadIdx.x;
  const int blk = blockIdx.x;

  if (t == 0) { s_c0 = 0; s_3f = 0; s_b1 = 0; s_odd = 0; }
  __syncthreads();
  // fmode self-detect (every block; 256B of x prefix, L2-broadcast after first)
  if (t < 128) {
    unsigned short u = ((const unsigned short*)x)[2 * t];
    int e = (u >> 7) & 0xFF;
    if (e >= 64 && e <= 150) atomicAdd(&s_c0, 1);
  }

  if (blk < 128) {
    // ============ prep: A_t repack via coalesced LDS transpose ============
    {
      int f3 = 0, b1 = 0, od = 0;
      for (int i = t; i < 2176; i += 256) {
        unsigned char bb = mr[i];
        if (bb == 0x3F) f3 = 1;
        if (bb) { if ((i & 3) == 1) b1 = 1; if (i & 3) od = 1; }
      }
      if (f3) atomicOr(&s_3f, 1);
      if (b1) atomicOr(&s_b1, 1);
      if (od) atomicOr(&s_odd, 1);
    }
    __syncthreads();
    const int fmode = (s_c0 >= 96) ? 0 : 1;
    const int mmode = s_3f ? (s_b1 ? 2 : 3) : (s_odd ? 0 : 1);
    unsigned short* At = (unsigned short*)(ws + OFF_AT);
    float* sL = (float*)As;                 // 1088 f32 = 4352 B staging
    // 128 mn-rows per block, 2 groups of 64: coalesced read -> LDS -> coalesced write
    for (int gi = 0; gi < 2; gi++) {
      int mn0 = blk * 128 + gi * 64;
      for (int j = t; j < 1088; j += 256)
        sL[j] = fmode ? ((const float*)as)[(size_t)mn0 * 17 + j]
                      : bf2f(((const unsigned short*)as)[(size_t)mn0 * 17 + j]);
      __syncthreads();
      for (int w = t; w < 1088; w += 256) {
        int r = w >> 6, jj = w & 63;
        At[(size_t)r * 16384 + mn0 + jj] = f2bf(sL[jj * 17 + r]);
      }
      __syncthreads();
    }
    // proj_w -> bf16 Pb (each prep block converts its 2048-element slice)
    {
      unsigned short* Pb = (unsigned short*)(ws + OFF_PW);
      const size_t pbase = (size_t)blk * 2048;
      if (fmode) {
        const float4* pwf = (const float4*)((const float*)pw + pbase);
        for (int j = t; j < 512; j += 256) {
          float4 v = pwf[j];
          ushort4 o;
          o.x = f2bf(v.x); o.y = f2bf(v.y); o.z = f2bf(v.z); o.w = f2bf(v.w);
          *(ushort4*)&Pb[pbase + (size_t)j * 4] = o;
        }
      } else {
        const ushort4* pwu = (const ushort4*)((const unsigned short*)pw + pbase);
        for (int j = t; j < 512; j += 256)
          *(ushort4*)&Pb[pbase + (size_t)j * 4] = pwu[j];
      }
    }
    // f32 mode: init out rows with bias (fused-atomic proj adds into it)
    if (fmode) {
      float* of = (float*)outp + (size_t)blk * 16 * 512;
      const float* pbf = (const float*)pb;
      for (int j = t; j < 8192; j += 256) of[j] = pbf[j & 511];
    }
    if (blk == 0) {
      if (t == 0) { ((int*)ws)[0] = fmode; ((int*)ws)[1] = mmode; }
      unsigned int* MB = (unsigned int*)(ws + OFF_MB);
      float* RBf = (float*)(ws + OFF_RBF);
      float* PBf = (float*)(ws + OFF_PBF);
      if (t < 128) {
        unsigned int bits = 0;
        for (int r = 0; r < 17; r++) {
          int j = t * 17 + r, v;
          if (mmode == 0)      v = mr[j] != 0;
          else if (mmode == 1) v = ((const int*)mr)[j] != 0;
          else if (mmode == 2) v = ((const unsigned short*)mr)[j] != 0;
          else                 v = ((const float*)mr)[j] != 0.0f;
          bits |= (unsigned int)v << r;
        }
        MB[t] = bits;
      }
      for (int j = t; j < 136; j += 256)
        RBf[j] = fmode ? ((const float*)rb)[j] : bf2f(((const unsigned short*)rb)[j]);
      for (int j = t; j < 512; j += 256)
        PBf[j] = fmode ? ((const float*)pb)[j] : bf2f(((const unsigned short*)pb)[j]);
    }
  } else {
    // ============ qkv GEMM: C[2048,1536] = x @ [qw;kvw]^T, 64x64 tile ============
    __syncthreads();
    const int fmode = (s_c0 >= 96) ? 0 : 1;
    const int gb2 = blk - 128;
    const int bm = (gb2 & 31) * 64, bn = (gb2 >> 5) * 64;
    const int wv = t >> 6, l = t & 63, ln = l & 15, qd = l >> 4;
    f32x4 acc[4] = {};
    const int g_row8 = l >> 3;
    const int g_ck = (l & 7) ^ g_row8;
    const int s_row = t >> 2;
    const int s_cb = (t & 3) * 2;
    for (int k0 = 0; k0 < 512; k0 += 64) {
      if (!fmode) {
        const unsigned short* xb = (const unsigned short*)x;
#pragma unroll
        for (int jj = 0; jj < 2; jj++) {
          int j = 2 * wv + jj;
          const unsigned short* g = xb + (size_t)(bm + j * 8 + g_row8) * 512 + k0 + g_ck * 8;
          __builtin_amdgcn_global_load_lds(
              (const __attribute__((address_space(1))) unsigned int*)g,
              (__attribute__((address_space(3))) unsigned int*)(&As[j * 512 + l * 8]),
              16, 0, 0);
        }
#pragma unroll
        for (int jj = 0; jj < 2; jj++) {
          int j = 2 * wv + jj;
          int row = bn + j * 8 + g_row8;
          const unsigned short* base = (row < 512)
              ? (const unsigned short*)qw + (size_t)row * 512
              : (const unsigned short*)kvw + (size_t)(row - 512) * 512;
          const unsigned short* g = base + k0 + g_ck * 8;
          __builtin_amdgcn_global_load_lds(
              (const __attribute__((address_space(1))) unsigned int*)g,
              (__attribute__((address_space(3))) unsigned int*)(&Bs[j * 512 + l * 8]),
              16, 0, 0);
        }
      } else {
        const float* ga = (const float*)x + (size_t)(bm + s_row) * 512 + k0 + s_cb * 8;
        int brow = bn + s_row;
        const float* gb = ((brow < 512) ? (const float*)qw + (size_t)brow * 512
                                        : (const float*)kvw + (size_t)(brow - 512) * 512)
                          + k0 + s_cb * 8;
#pragma unroll
        for (int cc = 0; cc < 2; cc++) {
          unsigned short ta[8], tb[8];
#pragma unroll
          for (int u = 0; u < 8; u++) { ta[u] = f2bf(ga[cc * 8 + u]); tb[u] = f2bf(gb[cc * 8 + u]); }
          int pc = (s_cb + cc) ^ (s_row & 7);
          *(uint4*)&As[s_row * 64 + pc * 8] = *(const uint4*)ta;
          *(uint4*)&Bs[s_row * 64 + pc * 8] = *(const uint4*)tb;
        }
      }
      __syncthreads();
#pragma unroll
      for (int kk = 0; kk < 64; kk += 32) {
        int c = (kk >> 3) + qd;
        short8 af = *(const short8*)&As[(wv * 16 + ln) * 64 + ((c ^ (ln & 7)) * 8)];
#pragma unroll
        for (int tj = 0; tj < 4; tj++) {
          short8 bf = *(const short8*)&Bs[(tj * 16 + ln) * 64 + ((c ^ (ln & 7)) * 8)];
          acc[tj] = __builtin_amdgcn_mfma_f32_16x16x32_bf16(af, bf, acc[tj], 0, 0, 0);
        }
      }
      __syncthreads();
    }
    unsigned short* XQ = (unsigned short*)(ws + OFF_XQ);
    unsigned short* VT = (unsigned short*)(ws + OFF_VT);
#pragma unroll
    for (int tj = 0; tj < 4; tj++) {
      int col = bn + tj * 16 + ln;
      if (col >= 1024) {                       // V -> transposed, packed 8B store
        int c1 = col - 1024;
        int row0 = bm + wv * 16 + qd * 4;
        int bh = (row0 >> 7) * 8 + (c1 >> 6);
        ushort4 pk;
        pk.x = f2bf(acc[tj][0]); pk.y = f2bf(acc[tj][1]);
        pk.z = f2bf(acc[tj][2]); pk.w = f2bf(acc[tj][3]);
        *(ushort4*)&VT[((size_t)bh * 64 + (c1 & 63)) * 128 + (row0 & 127)] = pk;
      } else {
#pragma unroll
        for (int i = 0; i < 4; i++) {
          int row = bm + wv * 16 + qd * 4 + i;
          XQ[(size_t)row * 1024 + col] = f2bf(acc[tj][i]);
        }
      }
    }
  }
}

// ---- attention core: 1024 blocks x 16 m-rows, ~10.8KB LDS, 4 blocks/CU ----
// No k/q LDS staging: each k-row/q-row fragment is consumed exactly once per
// wave, so S-phase MFMA fragments gather directly from XQ (16 rows x 64B per
// instr, same pattern as the VT reads). Softmax reduction: 4 DPP adds +
// 1 ds_swizzle (xor16) instead of 5 ds_bpermute shfls.
// FUSED=1 (f32 harness): proj partial in-block + unsafeAtomicAdd into out.
// FUSED=0 (bf16 harness): writes bf16 ATTO; k_proj follows.
#define SST 132    // f32 per S row (pad); W bf16 overlays same rows (stride 264 u16)

template <int FUSED>
__global__ __launch_bounds__(512) void k_attn(
    const unsigned short* __restrict__ XQ, const unsigned short* __restrict__ VT,
    const unsigned short* __restrict__ AT, const unsigned int* __restrict__ MB,
    const float* __restrict__ RBf, const unsigned short* __restrict__ Pb,
    unsigned short* __restrict__ ATTO, float* __restrict__ out) {
  __shared__ __align__(16) float Sf[16 * SST];          // 8448 B
  __shared__ __align__(16) unsigned short attL[16][72]; // 2304 B
  unsigned short* Wb = (unsigned short*)Sf;

  // 1024 blocks = (slot 0..127) x (xcd 0..7); m-eighth pinned to one XCD
  // -> per-L2 A_t hot set = 69 KB; proj atomics land on the local XCD.
  const int i0 = blockIdx.x;
  const int xcd = i0 & 7, slot = i0 >> 3;
  const int mq = xcd;                      // 0..7 (16 m-rows each)
  const int bhid = slot;                   // 0..127
  const int h = bhid & 7, b = bhid >> 3;
  const int bh = b * 8 + h;
  const int t = threadIdx.x;
  const int wv = t >> 6, l = t & 63, ln = l & 15, qd = l >> 4;

  // softmax ids (also used for early A prefetch): 32 thr/row x 4 n-vals
  const int ml = t >> 5, q32 = t & 31, n0 = q32 * 4;
  const int m = mq * 16 + ml;
  const unsigned short* abase = AT + (size_t)m * 128 + n0;
  // early prefetch: first TWO A planes + mask bits issued before S-phase
  uint2 ca = *(const uint2*)abase;
  uint2 cb = *(const uint2*)(abase + 16384);
  const unsigned int mb = MB[m];

  // ---- S(16x128) = q @ k^T * scale : 8 waves, one 16x16 tile each;
  //      fragments gathered directly from XQ (no LDS staging) ----
  {
    const unsigned short* xqb = XQ + (size_t)(b * 128) * 1024 + h * 64;
    const unsigned short* qrow = xqb + (size_t)(mq * 16 + ln) * 1024;
    const unsigned short* krow = xqb + 512 + (size_t)(wv * 16 + ln) * 1024;
    f32x4 accS = {};
#pragma unroll
    for (int kk = 0; kk < 64; kk += 32) {
      short8 af = *(const short8*)(qrow + kk + qd * 8);
      short8 bf = *(const short8*)(krow + kk + qd * 8);
      accS = __builtin_amdgcn_mfma_f32_16x16x32_bf16(af, bf, accS, 0, 0, 0);
    }
#pragma unroll
    for (int i = 0; i < 4; i++)
      Sf[(qd * 4 + i) * SST + wv * 16 + ln] = accS[i] * 0.125f;
  }
  __syncthreads();

  // ---- fused single-pass logits+softmax+W : 32 thr/row x 4 n-values ----
  // max-free softmax: logits O(10) << 88 (fp32 exp limit); dividing by the sum
  // afterwards is mathematically identical to ref softmax.
  {
    const float* rbh = RBf + h * 17;
    float sreg[4];
    {
      float4 s4 = *(const float4*)&Sf[ml * SST + n0];
      sreg[0] = s4.x; sreg[1] = s4.y; sreg[2] = s4.z; sreg[3] = s4.w;
    }
    float wacc[4];
#pragma unroll
    for (int j = 0; j < 4; j++) wacc[j] = 0.0f;
    float sum = 0.0f;
#pragma unroll
    for (int r = 0; r < 17; r++) {
      uint2 nn;
      if (r + 2 < 17) nn = *(const uint2*)(abase + (r + 2) * 16384);
      float av[4];
      const unsigned short* a8 = (const unsigned short*)&ca;
#pragma unroll
      for (int j = 0; j < 4; j++) av[j] = bf2f(a8[j]);
      float s = sreg[0] * av[0] + sreg[1] * av[1] + sreg[2] * av[2] + sreg[3] * av[3];
      // 32-lane sum: 4 DPP adds (VALU) + 1 swizzle (xor16) — was 5 ds_bpermute
      s += dppf<0xB1>(s);                    // quad_perm [1,0,3,2]  (xor 1)
      s += dppf<0x4E>(s);                    // quad_perm [2,3,0,1]  (xor 2)
      s += dppf<0x124>(s);                   // row_ror:4
      s += dppf<0x128>(s);                   // row_ror:8
      s += __int_as_float(__builtin_amdgcn_ds_swizzle(__float_as_int(s), 0x401F));
      float e = ((mb >> r) & 1) ? 0.0f : __expf(s + rbh[r]);
      sum += e;
#pragma unroll
      for (int j = 0; j < 4; j++) wacc[j] += e * av[j];
      ca = cb; cb = nn;
    }
    const float inv = 1.0f / sum;
    unsigned short pk[4];
#pragma unroll
    for (int j = 0; j < 4; j++) pk[j] = f2bf(wacc[j] * inv);
    // W overlays same-row S bytes; the row's 32 threads live in one half-wave
    // and all S reads precede these writes in program order
    *(uint2*)&Wb[ml * 264 + n0] = *(const uint2*)&pk[0];
  }
  __syncthreads();

  if constexpr (!FUSED) {
    // ---- out(16x64) = W(16x128) @ v(128x64) -> global ATTO (bf16 path) ----
    if (wv < 4) {
      f32x4 accO = {};
      const int d = wv * 16 + ln;
      const unsigned short* vrow = VT + ((size_t)bh * 64 + d) * 128;
#pragma unroll
      for (int kk = 0; kk < 128; kk += 32) {
        short8 af = *(const short8*)&Wb[ln * 264 + kk + qd * 8];
        short8 bf = *(const short8*)(vrow + kk + qd * 8);
        accO = __builtin_amdgcn_mfma_f32_16x16x32_bf16(af, bf, accO, 0, 0, 0);
      }
#pragma unroll
      for (int i = 0; i < 4; i++) {
        int row = b * 128 + mq * 16 + qd * 4 + i;
        ATTO[(size_t)row * 512 + h * 64 + (wv * 16 + ln)] = f2bf(accO[i]);
      }
    }
  } else {
    // ---- out(16x64) = W @ v -> LDS attL ----
    if (wv < 4) {
      f32x4 accO = {};
      const int d = wv * 16 + ln;
      const unsigned short* vrow = VT + ((size_t)bh * 64 + d) * 128;
#pragma unroll
      for (int kk = 0; kk < 128; kk += 32) {
        short8 af = *(const short8*)&Wb[ln * 264 + kk + qd * 8];
        short8 bf = *(const short8*)(vrow + kk + qd * 8);
        accO = __builtin_amdgcn_mfma_f32_16x16x32_bf16(af, bf, accO, 0, 0, 0);
      }
#pragma unroll
      for (int i = 0; i < 4; i++)
        attL[qd * 4 + i][d] = f2bf(accO[i]);
    }
    __syncthreads();

    // ---- fused proj partial: att(16x64) @ proj_w[:, h*64:+64]^T, all 8 waves;
    //      wave wv owns output cols wv*64..+63; atomic-add into bias-inited out.
    short8 afk0 = *(const short8*)&attL[ln][qd * 8];
    short8 afk1 = *(const short8*)&attL[ln][32 + qd * 8];
    float* orow = out + (size_t)(b * 128 + mq * 16) * 512;
#pragma unroll
    for (int tj = 0; tj < 4; tj++) {
      const unsigned short* prow = Pb + (size_t)(wv * 64 + tj * 16 + ln) * 512 + h * 64;
      short8 bf0 = *(const short8*)(prow + qd * 8);
      short8 bf1 = *(const short8*)(prow + 32 + qd * 8);
      f32x4 p = {};
      p = __builtin_amdgcn_mfma_f32_16x16x32_bf16(afk0, bf0, p, 0, 0, 0);
      p = __builtin_amdgcn_mfma_f32_16x16x32_bf16(afk1, bf1, p, 0, 0, 0);
#pragma unroll
      for (int i = 0; i < 4; i++)
        unsafeAtomicAdd(&orow[(size_t)(qd * 4 + i) * 512 + wv * 64 + tj * 16 + ln], p[i]);
    }
  }
}

// ---- proj GEMM (bf16 path only): 64x32 tiles, 512 blocks ----
__global__ __launch_bounds__(256) void k_proj(
    const unsigned short* __restrict__ A,   // ATTO bf16 [2048][512]
    const void* __restrict__ Bw,            // proj_w raw
    const float* __restrict__ biasf,
    const int* __restrict__ flags, void* __restrict__ C) {
  __shared__ unsigned short As[64 * 64];
  __shared__ unsigned short Bs[32 * 64];
  const int fmode = flags[0];
  const int bm = blockIdx.x * 64, bn = blockIdx.y * 32;
  const int t = threadIdx.x, wv = t >> 6, l = t & 63, ln = l & 15, qd = l >> 4;
  f32x4 acc[2] = {};
  const int g_row8 = l >> 3;
  const int g_ck = (l & 7) ^ g_row8;
  for (int k0 = 0; k0 < 512; k0 += 64) {
#pragma unroll
    for (int jj = 0; jj < 2; jj++) {
      int j = 2 * wv + jj;
      const unsigned short* g = A + (size_t)(bm + j * 8 + g_row8) * 512 + k0 + g_ck * 8;
      __builtin_amdgcn_global_load_lds(
          (const __attribute__((address_space(1))) unsigned int*)g,
          (__attribute__((address_space(3))) unsigned int*)(&As[j * 512 + l * 8]),
          16, 0, 0);
    }
    if (!fmode) {
      int row = bn + wv * 8 + g_row8;
      const unsigned short* g = (const unsigned short*)Bw + (size_t)row * 512 + k0 + g_ck * 8;
      __builtin_amdgcn_global_load_lds(
          (const __attribute__((address_space(1))) unsigned int*)g,
          (__attribute__((address_space(3))) unsigned int*)(&Bs[wv * 512 + l * 8]),
          16, 0, 0);
    } else {
      int row = t >> 3, cb = t & 7;     // 32 rows x 8 chunks
      const float* g = (const float*)Bw + (size_t)(bn + row) * 512 + k0 + cb * 8;
      unsigned short tb[8];
#pragma unroll
      for (int u = 0; u < 8; u++) tb[u] = f2bf(g[u]);
      int pc = cb ^ (row & 7);
      *(uint4*)&Bs[row * 64 + pc * 8] = *(const uint4*)tb;
    }
    __syncthreads();
#pragma unroll
    for (int kk = 0; kk < 64; kk += 32) {
      int c = (kk >> 3) + qd;
      short8 af = *(const short8*)&As[(wv * 16 + ln) * 64 + ((c ^ (ln & 7)) * 8)];
#pragma unroll
      for (int tj = 0; tj < 2; tj++) {
        short8 bf = *(const short8*)&Bs[(tj * 16 + ln) * 64 + ((c ^ (ln & 7)) * 8)];
        acc[tj] = __builtin_amdgcn_mfma_f32_16x16x32_bf16(af, bf, acc[tj], 0, 0, 0);
      }
    }
    __syncthreads();
  }
#pragma unroll
  for (int tj = 0; tj < 2; tj++) {
    int col = bn + tj * 16 + ln;
    float bv = biasf[col];
#pragma unroll
    for (int i = 0; i < 4; i++) {
      int row = bm + wv * 16 + qd * 4 + i;
      float v = acc[tj][i] + bv;
      if (fmode) ((float*)C)[(size_t)row * 512 + col] = v;
      else       ((unsigned short*)C)[(size_t)row * 512 + col] = f2bf(v);
    }
  }
}

extern "C" void kernel_launch(void* const* d_in, const int* in_sizes, int n_in,
                              void* d_out, int out_size, void* d_ws, size_t ws_size,
                              hipStream_t stream) {
  unsigned char* ws = (unsigned char*)d_ws;
  // 0:x 1:assignment 2:mask 3:q_w 4:kv_w 5:rel_bias 6:proj_w 7:proj_b
  // dtype dispatch at capture time: x f32 = 16*128*512*4 bytes
  const bool f32in = (in_sizes[0] >= 16 * 128 * 512 * 4);
  k_phase1<<<896, 256, 0, stream>>>(d_in[0], d_in[3], d_in[4], d_in[1],
                                    (const unsigned char*)d_in[2],
                                    d_in[5], d_in[7], d_in[6], ws, d_out);
  if (f32in) {
    k_attn<1><<<1024, 512, 0, stream>>>(
        (const unsigned short*)(ws + OFF_XQ),
        (const unsigned short*)(ws + OFF_VT),
        (const unsigned short*)(ws + OFF_AT),
        (const unsigned int*)(ws + OFF_MB),
        (const float*)(ws + OFF_RBF),
        (const unsigned short*)(ws + OFF_PW),
        nullptr, (float*)d_out);
  } else {
    k_attn<0><<<1024, 512, 0, stream>>>(
        (const unsigned short*)(ws + OFF_XQ),
        (const unsigned short*)(ws + OFF_VT),
        (const unsigned short*)(ws + OFF_AT),
        (const unsigned int*)(ws + OFF_MB),
        (const float*)(ws + OFF_RBF),
        nullptr, (unsigned short*)(ws + OFF_ATTO), nullptr);
    k_proj<<<dim3(32, 16), 256, 0, stream>>>(
        (const unsigned short*)(ws + OFF_ATTO), d_in[6],
        (const float*)(ws + OFF_PBF), (const int*)ws, d_out);
  }
}

// Round 4
// 113.724 us; speedup vs baseline: 3.5907x; 1.0093x over previous
//
#include <hip/hip_runtime.h>
#include <cstdint>
#include <cstddef>

#define DI __device__ __forceinline__

typedef __attribute__((ext_vector_type(8))) short short8;
typedef __attribute__((ext_vector_type(4))) float f32x4;

DI float bf2f(unsigned short u) {
  union { unsigned int i; float f; } c; c.i = ((unsigned int)u) << 16; return c.f;
}
DI unsigned short f2bf(float f) {
  union { float fl; unsigned int i; } c; c.fl = f;
  return (unsigned short)((c.i + 0x7FFFu + ((c.i >> 16) & 1u)) >> 16);
}
// HW packed f32->bf16 (RTNE), 1 VALU op for 2 converts. lo -> D[15:0], hi -> D[31:16].
DI unsigned int cvtpk(float lo, float hi) {
  unsigned int r;
  asm("v_cvt_pk_bf16_f32 %0, %1, %2" : "=v"(r) : "v"(lo), "v"(hi));
  return r;
}

// DPP lane-shuffled copy (quad_perm / row_ror): full-rate VALU, no LDS pipe.
template <int CTRL>
DI float dppf(float v) {
  return __int_as_float(__builtin_amdgcn_update_dpp(
      0, __float_as_int(v), CTRL, 0xF, 0xF, true));
}

// ---- workspace layout (bytes) ----
static const size_t OFF_MB   = 256;                       // u32[128] mask bitwords
static const size_t OFF_RBF  = 1024;                      // f32[136] rel_bias
static const size_t OFF_PBF  = 2048;                      // f32[512] proj_b
static const size_t OFF_AT   = 16384;                     // bf16 A_t[17][128][128]
static const size_t OFF_XQ   = OFF_AT + 557056;           // bf16 [2048][1024] (q|k)
static const size_t OFF_VT   = OFF_XQ + (size_t)4194304;  // bf16 [128bh][64d][128n]
static const size_t OFF_ATTO = OFF_VT + (size_t)2097152;  // bf16 [2048][512] (bf16 path only)
static const size_t OFF_PW   = OFF_ATTO + (size_t)2097152; // bf16 proj_w [512][512]

// ---- phase1: blocks 0..127 prep (dispatch-first => starts early);
//              blocks 128..895 qkv GEMM (64x64 tile, ~3 blocks/CU) ----
__global__ __launch_bounds__(256) void k_phase1(
    const void* __restrict__ x, const void* __restrict__ qw,
    const void* __restrict__ kvw, const void* __restrict__ as,
    const unsigned char* __restrict__ mr, const void* __restrict__ rb,
    const void* __restrict__ pb, const void* __restrict__ pw,
    unsigned char* __restrict__ ws, void* __restrict__ outp) {
  __shared__ unsigned short As[64 * 64];
  __shared__ unsigned short Bs[64 * 64];
  __shared__ int s_c0, s_3f, s_b1, s_odd;
  const int t = threadIdx.x;
  const int blk = blockIdx.x;

  if (t == 0) { s_c0 = 0; s_3f = 0; s_b1 = 0; s_odd = 0; }
  __syncthreads();
  // fmode self-detect (every block; 256B of x prefix, L2-broadcast after first)
  if (t < 128) {
    unsigned short u = ((const unsigned short*)x)[2 * t];
    int e = (u >> 7) & 0xFF;
    if (e >= 64 && e <= 150) atomicAdd(&s_c0, 1);
  }

  if (blk < 128) {
    // ============ prep: A_t repack via coalesced LDS transpose ============
    {
      int f3 = 0, b1 = 0, od = 0;
      for (int i = t; i < 2176; i += 256) {
        unsigned char bb = mr[i];
        if (bb == 0x3F) f3 = 1;
        if (bb) { if ((i & 3) == 1) b1 = 1; if (i & 3) od = 1; }
      }
      if (f3) atomicOr(&s_3f, 1);
      if (b1) atomicOr(&s_b1, 1);
      if (od) atomicOr(&s_odd, 1);
    }
    __syncthreads();
    const int fmode = (s_c0 >= 96) ? 0 : 1;
    const int mmode = s_3f ? (s_b1 ? 2 : 3) : (s_odd ? 0 : 1);
    unsigned short* At = (unsigned short*)(ws + OFF_AT);
    float* sL = (float*)As;                 // 1088 f32 = 4352 B staging
    // 128 mn-rows per block, 2 groups of 64: coalesced read -> LDS -> coalesced write
    for (int gi = 0; gi < 2; gi++) {
      int mn0 = blk * 128 + gi * 64;
      for (int j = t; j < 1088; j += 256)
        sL[j] = fmode ? ((const float*)as)[(size_t)mn0 * 17 + j]
                      : bf2f(((const unsigned short*)as)[(size_t)mn0 * 17 + j]);
      __syncthreads();
      for (int w = t; w < 1088; w += 256) {
        int r = w >> 6, jj = w & 63;
        At[(size_t)r * 16384 + mn0 + jj] = f2bf(sL[jj * 17 + r]);
      }
      __syncthreads();
    }
    // proj_w -> bf16 Pb (each prep block converts its 2048-element slice)
    {
      unsigned short* Pb = (unsigned short*)(ws + OFF_PW);
      const size_t pbase = (size_t)blk * 2048;
      if (fmode) {
        const float4* pwf = (const float4*)((const float*)pw + pbase);
        for (int j = t; j < 512; j += 256) {
          float4 v = pwf[j];
          uint2 o;
          o.x = cvtpk(v.x, v.y); o.y = cvtpk(v.z, v.w);
          *(uint2*)&Pb[pbase + (size_t)j * 4] = o;
        }
      } else {
        const ushort4* pwu = (const ushort4*)((const unsigned short*)pw + pbase);
        for (int j = t; j < 512; j += 256)
          *(ushort4*)&Pb[pbase + (size_t)j * 4] = pwu[j];
      }
    }
    // f32 mode: init out rows with bias (fused-atomic proj adds into it)
    if (fmode) {
      float* of = (float*)outp + (size_t)blk * 16 * 512;
      const float* pbf = (const float*)pb;
      for (int j = t; j < 8192; j += 256) of[j] = pbf[j & 511];
    }
    if (blk == 0) {
      if (t == 0) { ((int*)ws)[0] = fmode; ((int*)ws)[1] = mmode; }
      unsigned int* MB = (unsigned int*)(ws + OFF_MB);
      float* RBf = (float*)(ws + OFF_RBF);
      float* PBf = (float*)(ws + OFF_PBF);
      if (t < 128) {
        unsigned int bits = 0;
        for (int r = 0; r < 17; r++) {
          int j = t * 17 + r, v;
          if (mmode == 0)      v = mr[j] != 0;
          else if (mmode == 1) v = ((const int*)mr)[j] != 0;
          else if (mmode == 2) v = ((const unsigned short*)mr)[j] != 0;
          else                 v = ((const float*)mr)[j] != 0.0f;
          bits |= (unsigned int)v << r;
        }
        MB[t] = bits;
      }
      for (int j = t; j < 136; j += 256)
        RBf[j] = fmode ? ((const float*)rb)[j] : bf2f(((const unsigned short*)rb)[j]);
      for (int j = t; j < 512; j += 256)
        PBf[j] = fmode ? ((const float*)pb)[j] : bf2f(((const unsigned short*)pb)[j]);
    }
  } else {
    // ============ qkv GEMM: C[2048,1536] = x @ [qw;kvw]^T, 64x64 tile ============
    __syncthreads();
    const int fmode = (s_c0 >= 96) ? 0 : 1;
    const int gb2 = blk - 128;
    const int bm = (gb2 & 31) * 64, bn = (gb2 >> 5) * 64;
    const int wv = t >> 6, l = t & 63, ln = l & 15, qd = l >> 4;
    f32x4 acc[4] = {};
    const int g_row8 = l >> 3;
    const int g_ck = (l & 7) ^ g_row8;
    const int s_row = t >> 2;
    const int s_cb = (t & 3) * 2;
    for (int k0 = 0; k0 < 512; k0 += 64) {
      if (!fmode) {
        const unsigned short* xb = (const unsigned short*)x;
#pragma unroll
        for (int jj = 0; jj < 2; jj++) {
          int j = 2 * wv + jj;
          const unsigned short* g = xb + (size_t)(bm + j * 8 + g_row8) * 512 + k0 + g_ck * 8;
          __builtin_amdgcn_global_load_lds(
              (const __attribute__((address_space(1))) unsigned int*)g,
              (__attribute__((address_space(3))) unsigned int*)(&As[j * 512 + l * 8]),
              16, 0, 0);
        }
#pragma unroll
        for (int jj = 0; jj < 2; jj++) {
          int j = 2 * wv + jj;
          int row = bn + j * 8 + g_row8;
          const unsigned short* base = (row < 512)
              ? (const unsigned short*)qw + (size_t)row * 512
              : (const unsigned short*)kvw + (size_t)(row - 512) * 512;
          const unsigned short* g = base + k0 + g_ck * 8;
          __builtin_amdgcn_global_load_lds(
              (const __attribute__((address_space(1))) unsigned int*)g,
              (__attribute__((address_space(3))) unsigned int*)(&Bs[j * 512 + l * 8]),
              16, 0, 0);
        }
      } else {
        const float* ga = (const float*)x + (size_t)(bm + s_row) * 512 + k0 + s_cb * 8;
        int brow = bn + s_row;
        const float* gb = ((brow < 512) ? (const float*)qw + (size_t)brow * 512
                                        : (const float*)kvw + (size_t)(brow - 512) * 512)
                          + k0 + s_cb * 8;
#pragma unroll
        for (int cc = 0; cc < 2; cc++) {
          unsigned int ta[4], tb[4];
#pragma unroll
          for (int u = 0; u < 4; u++) {
            ta[u] = cvtpk(ga[cc * 8 + 2 * u], ga[cc * 8 + 2 * u + 1]);
            tb[u] = cvtpk(gb[cc * 8 + 2 * u], gb[cc * 8 + 2 * u + 1]);
          }
          int pc = (s_cb + cc) ^ (s_row & 7);
          *(uint4*)&As[s_row * 64 + pc * 8] = *(const uint4*)ta;
          *(uint4*)&Bs[s_row * 64 + pc * 8] = *(const uint4*)tb;
        }
      }
      __syncthreads();
#pragma unroll
      for (int kk = 0; kk < 64; kk += 32) {
        int c = (kk >> 3) + qd;
        short8 af = *(const short8*)&As[(wv * 16 + ln) * 64 + ((c ^ (ln & 7)) * 8)];
#pragma unroll
        for (int tj = 0; tj < 4; tj++) {
          short8 bf = *(const short8*)&Bs[(tj * 16 + ln) * 64 + ((c ^ (ln & 7)) * 8)];
          acc[tj] = __builtin_amdgcn_mfma_f32_16x16x32_bf16(af, bf, acc[tj], 0, 0, 0);
        }
      }
      __syncthreads();
    }
    unsigned short* XQ = (unsigned short*)(ws + OFF_XQ);
    unsigned short* VT = (unsigned short*)(ws + OFF_VT);
#pragma unroll
    for (int tj = 0; tj < 4; tj++) {
      int col = bn + tj * 16 + ln;
      unsigned int p01 = cvtpk(acc[tj][0], acc[tj][1]);
      unsigned int p23 = cvtpk(acc[tj][2], acc[tj][3]);
      if (col >= 1024) {                       // V -> transposed, packed 8B store
        int c1 = col - 1024;
        int row0 = bm + wv * 16 + qd * 4;
        int bh = (row0 >> 7) * 8 + (c1 >> 6);
        uint2 pk2; pk2.x = p01; pk2.y = p23;
        *(uint2*)&VT[((size_t)bh * 64 + (c1 & 63)) * 128 + (row0 & 127)] = pk2;
      } else {
        int row0 = bm + wv * 16 + qd * 4;
        XQ[(size_t)(row0 + 0) * 1024 + col] = (unsigned short)p01;
        XQ[(size_t)(row0 + 1) * 1024 + col] = (unsigned short)(p01 >> 16);
        XQ[(size_t)(row0 + 2) * 1024 + col] = (unsigned short)p23;
        XQ[(size_t)(row0 + 3) * 1024 + col] = (unsigned short)(p23 >> 16);
      }
    }
  }
}

// ======== f32-path attention+proj: 256 blocks = (b 16) x (half 2) x (mq 8) ========
// 4 heads per block. Zero duplication in S/softmax/PV (heads partition);
// proj K=512 splits contiguously across the two half-blocks (2 atomics/element,
// was 8). One A_t 17-plane pass feeds all 4 heads' softmax (4x less A traffic).
#define SST4 132   // f32 per S row (pad); W bf16 overlays same rows (stride 264 u16)
#define ATS 272    // att row stride in u16

__global__ __launch_bounds__(512) void k_attn_f32(
    const unsigned short* __restrict__ XQ, const unsigned short* __restrict__ VT,
    const unsigned short* __restrict__ AT, const unsigned int* __restrict__ MB,
    const float* __restrict__ RBf, const unsigned short* __restrict__ Pb,
    float* __restrict__ out) {
  __shared__ __align__(16) float Sf[4 * 16 * SST4];        // 33792 B
  __shared__ __align__(16) unsigned short att[16 * ATS];   // 8704 B
  __shared__ float rbl[72];
  unsigned short* Wb = (unsigned short*)Sf;   // [4][16][264] u16 overlay

  const int i0 = blockIdx.x;                 // 256 blocks, 1/CU
  const int xcd = i0 & 7, slot = i0 >> 3;    // mq pinned to XCD: A_t slice + out
  const int mq = xcd;                        //   atomics stay L2-local; both
  const int b = slot >> 1, half = slot & 1;  //   halves of a group same XCD.
  const int h0 = half * 4;
  const int t = threadIdx.x;
  const int wv = t >> 6, l = t & 63, ln = l & 15, qd = l >> 4;
  const int ml = t >> 5, q32 = t & 31, n0 = q32 * 4;

  const int m = mq * 16 + ml;
  const unsigned short* abase = AT + (size_t)m * 128 + n0;
  // early prefetch: first TWO A planes + mask bits + rel_bias slice
  uint2 ca = *(const uint2*)abase;
  uint2 cb = *(const uint2*)(abase + 16384);
  const unsigned int mb = MB[m];
  if (t < 68) rbl[t] = RBf[h0 * 17 + t];

  // ---- S: wave w -> head hh=w>>1, 4 n-tiles; frags direct from XQ ----
  {
    const int hh = wv >> 1;
    const unsigned short* qrow =
        XQ + (size_t)(b * 128 + mq * 16 + ln) * 1024 + (h0 + hh) * 64;
    short8 af0 = *(const short8*)(qrow + qd * 8);
    short8 af1 = *(const short8*)(qrow + 32 + qd * 8);
    const int ntb = (wv & 1) * 4;
#pragma unroll
    for (int u = 0; u < 4; u++) {
      const int nt = ntb + u;
      const unsigned short* krow =
          XQ + (size_t)(b * 128 + nt * 16 + ln) * 1024 + 512 + (h0 + hh) * 64;
      short8 bf0 = *(const short8*)(krow + qd * 8);
      short8 bf1 = *(const short8*)(krow + 32 + qd * 8);
      f32x4 accS = {};
      accS = __builtin_amdgcn_mfma_f32_16x16x32_bf16(af0, bf0, accS, 0, 0, 0);
      accS = __builtin_amdgcn_mfma_f32_16x16x32_bf16(af1, bf1, accS, 0, 0, 0);
#pragma unroll
      for (int i = 0; i < 4; i++)
        Sf[(hh * 16 + qd * 4 + i) * SST4 + nt * 16 + ln] = accS[i] * 0.125f;
    }
  }
  __syncthreads();

  // ---- fused softmax+W for all 4 heads in ONE 17-plane A pass ----
  // max-free softmax: logits O(10) << 88 (fp32 exp limit).
  {
    float sreg[4][4];
#pragma unroll
    for (int hh = 0; hh < 4; hh++) {
      float4 s4 = *(const float4*)&Sf[(hh * 16 + ml) * SST4 + n0];
      sreg[hh][0] = s4.x; sreg[hh][1] = s4.y; sreg[hh][2] = s4.z; sreg[hh][3] = s4.w;
    }
    float wacc[4][4] = {};
    float sum[4] = {};
#pragma unroll
    for (int r = 0; r < 17; r++) {
      uint2 nn;
      if (r + 2 < 17) nn = *(const uint2*)(abase + (r + 2) * 16384);
      float av[4];
      const unsigned short* a8 = (const unsigned short*)&ca;
#pragma unroll
      for (int j = 0; j < 4; j++) av[j] = bf2f(a8[j]);
      const int msk = (mb >> r) & 1;
#pragma unroll
      for (int hh = 0; hh < 4; hh++) {
        float s = sreg[hh][0] * av[0] + sreg[hh][1] * av[1] +
                  sreg[hh][2] * av[2] + sreg[hh][3] * av[3];
        // 32-lane sum: 4 DPP adds (VALU) + 1 swizzle (xor16); 4 chains ILP
        s += dppf<0xB1>(s);                    // quad_perm xor1
        s += dppf<0x4E>(s);                    // quad_perm xor2
        s += dppf<0x124>(s);                   // row_ror:4
        s += dppf<0x128>(s);                   // row_ror:8
        s += __int_as_float(__builtin_amdgcn_ds_swizzle(__float_as_int(s), 0x401F));
        float e = msk ? 0.0f : __expf(s + rbl[hh * 17 + r]);
        sum[hh] += e;
#pragma unroll
        for (int j = 0; j < 4; j++) wacc[hh][j] += e * av[j];
      }
      ca = cb; cb = nn;
    }
#pragma unroll
    for (int hh = 0; hh < 4; hh++) {
      const float inv = 1.0f / sum[hh];
      uint2 o;
      o.x = cvtpk(wacc[hh][0] * inv, wacc[hh][1] * inv);
      o.y = cvtpk(wacc[hh][2] * inv, wacc[hh][3] * inv);
      // W overlays same-row S bytes; row's 32 threads are one half-wave and
      // all S reads (sreg) precede these writes in program order
      *(uint2*)&Wb[(hh * 16 + ml) * 264 + n0] = o;
    }
  }
  __syncthreads();

  // ---- PV: 16 units (4 heads x 4 d-tiles) / 8 waves = 2 each -> att LDS ----
  {
#pragma unroll
    for (int uu = 0; uu < 2; uu++) {
      const int u = wv * 2 + uu, hh = u >> 2, dt = u & 3;
      const unsigned short* vrow =
          VT + ((size_t)(b * 8 + h0 + hh) * 64 + dt * 16 + ln) * 128;
      f32x4 accO = {};
#pragma unroll
      for (int kk = 0; kk < 128; kk += 32) {
        short8 afw = *(const short8*)&Wb[(hh * 16 + ln) * 264 + kk + qd * 8];
        short8 bfv = *(const short8*)(vrow + kk + qd * 8);
        accO = __builtin_amdgcn_mfma_f32_16x16x32_bf16(afw, bfv, accO, 0, 0, 0);
      }
      unsigned int p01 = cvtpk(accO[0], accO[1]);
      unsigned int p23 = cvtpk(accO[2], accO[3]);
      const int cc = hh * 64 + dt * 16 + ln;
      att[(qd * 4 + 0) * ATS + cc] = (unsigned short)p01;
      att[(qd * 4 + 1) * ATS + cc] = (unsigned short)(p01 >> 16);
      att[(qd * 4 + 2) * ATS + cc] = (unsigned short)p23;
      att[(qd * 4 + 3) * ATS + cc] = (unsigned short)(p23 >> 16);
    }
  }
  __syncthreads();

  // ---- proj partial (K=256 half): wave w -> out cols w*64..+63 ----
  {
    short8 afp[8];
#pragma unroll
    for (int kf = 0; kf < 8; kf++)
      afp[kf] = *(const short8*)&att[ln * ATS + kf * 32 + qd * 8];
    float* orow = out + (size_t)(b * 128 + mq * 16) * 512;
#pragma unroll
    for (int tj = 0; tj < 4; tj++) {
      const unsigned short* prow =
          Pb + (size_t)(wv * 64 + tj * 16 + ln) * 512 + half * 256;
      f32x4 p = {};
#pragma unroll
      for (int kf = 0; kf < 8; kf++) {
        short8 bfp = *(const short8*)(prow + kf * 32 + qd * 8);
        p = __builtin_amdgcn_mfma_f32_16x16x32_bf16(afp[kf], bfp, p, 0, 0, 0);
      }
#pragma unroll
      for (int i = 0; i < 4; i++)
        unsafeAtomicAdd(&orow[(size_t)(qd * 4 + i) * 512 + wv * 64 + tj * 16 + ln], p[i]);
    }
  }
}

// ---- bf16-path attention (round-3 structure): 1024 blocks -> ATTO ----
#define SST 132

__global__ __launch_bounds__(512) void k_attn_bf16(
    const unsigned short* __restrict__ XQ, const unsigned short* __restrict__ VT,
    const unsigned short* __restrict__ AT, const unsigned int* __restrict__ MB,
    const float* __restrict__ RBf, unsigned short* __restrict__ ATTO) {
  __shared__ __align__(16) float Sf[16 * SST];
  unsigned short* Wb = (unsigned short*)Sf;

  const int i0 = blockIdx.x;
  const int xcd = i0 & 7, slot = i0 >> 3;
  const int mq = xcd;
  const int bhid = slot;
  const int h = bhid & 7, b = bhid >> 3;
  const int bh = b * 8 + h;
  const int t = threadIdx.x;
  const int wv = t >> 6, l = t & 63, ln = l & 15, qd = l >> 4;
  const int ml = t >> 5, q32 = t & 31, n0 = q32 * 4;
  const int m = mq * 16 + ml;
  const unsigned short* abase = AT + (size_t)m * 128 + n0;
  uint2 ca = *(const uint2*)abase;
  uint2 cb = *(const uint2*)(abase + 16384);
  const unsigned int mb = MB[m];

  {
    const unsigned short* xqb = XQ + (size_t)(b * 128) * 1024 + h * 64;
    const unsigned short* qrow = xqb + (size_t)(mq * 16 + ln) * 1024;
    const unsigned short* krow = xqb + 512 + (size_t)(wv * 16 + ln) * 1024;
    f32x4 accS = {};
#pragma unroll
    for (int kk = 0; kk < 64; kk += 32) {
      short8 af = *(const short8*)(qrow + kk + qd * 8);
      short8 bf = *(const short8*)(krow + kk + qd * 8);
      accS = __builtin_amdgcn_mfma_f32_16x16x32_bf16(af, bf, accS, 0, 0, 0);
    }
#pragma unroll
    for (int i = 0; i < 4; i++)
      Sf[(qd * 4 + i) * SST + wv * 16 + ln] = accS[i] * 0.125f;
  }
  __syncthreads();

  {
    const float* rbh = RBf + h * 17;
    float sreg[4];
    {
      float4 s4 = *(const float4*)&Sf[ml * SST + n0];
      sreg[0] = s4.x; sreg[1] = s4.y; sreg[2] = s4.z; sreg[3] = s4.w;
    }
    float wacc[4] = {};
    float sum = 0.0f;
#pragma unroll
    for (int r = 0; r < 17; r++) {
      uint2 nn;
      if (r + 2 < 17) nn = *(const uint2*)(abase + (r + 2) * 16384);
      float av[4];
      const unsigned short* a8 = (const unsigned short*)&ca;
#pragma unroll
      for (int j = 0; j < 4; j++) av[j] = bf2f(a8[j]);
      float s = sreg[0] * av[0] + sreg[1] * av[1] + sreg[2] * av[2] + sreg[3] * av[3];
      s += dppf<0xB1>(s);
      s += dppf<0x4E>(s);
      s += dppf<0x124>(s);
      s += dppf<0x128>(s);
      s += __int_as_float(__builtin_amdgcn_ds_swizzle(__float_as_int(s), 0x401F));
      float e = ((mb >> r) & 1) ? 0.0f : __expf(s + rbh[r]);
      sum += e;
#pragma unroll
      for (int j = 0; j < 4; j++) wacc[j] += e * av[j];
      ca = cb; cb = nn;
    }
    const float inv = 1.0f / sum;
    uint2 o;
    o.x = cvtpk(wacc[0] * inv, wacc[1] * inv);
    o.y = cvtpk(wacc[2] * inv, wacc[3] * inv);
    *(uint2*)&Wb[ml * 264 + n0] = o;
  }
  __syncthreads();

  if (wv < 4) {
    f32x4 accO = {};
    const int d = wv * 16 + ln;
    const unsigned short* vrow = VT + ((size_t)bh * 64 + d) * 128;
#pragma unroll
    for (int kk = 0; kk < 128; kk += 32) {
      short8 af = *(const short8*)&Wb[ln * 264 + kk + qd * 8];
      short8 bf = *(const short8*)(vrow + kk + qd * 8);
      accO = __builtin_amdgcn_mfma_f32_16x16x32_bf16(af, bf, accO, 0, 0, 0);
    }
#pragma unroll
    for (int i = 0; i < 4; i++) {
      int row = b * 128 + mq * 16 + qd * 4 + i;
      ATTO[(size_t)row * 512 + h * 64 + d] = f2bf(accO[i]);
    }
  }
}

// ---- proj GEMM (bf16 path only): 64x32 tiles, 512 blocks ----
__global__ __launch_bounds__(256) void k_proj(
    const unsigned short* __restrict__ A,   // ATTO bf16 [2048][512]
    const void* __restrict__ Bw,            // proj_w raw
    const float* __restrict__ biasf,
    const int* __restrict__ flags, void* __restrict__ C) {
  __shared__ unsigned short As[64 * 64];
  __shared__ unsigned short Bs[32 * 64];
  const int fmode = flags[0];
  const int bm = blockIdx.x * 64, bn = blockIdx.y * 32;
  const int t = threadIdx.x, wv = t >> 6, l = t & 63, ln = l & 15, qd = l >> 4;
  f32x4 acc[2] = {};
  const int g_row8 = l >> 3;
  const int g_ck = (l & 7) ^ g_row8;
  for (int k0 = 0; k0 < 512; k0 += 64) {
#pragma unroll
    for (int jj = 0; jj < 2; jj++) {
      int j = 2 * wv + jj;
      const unsigned short* g = A + (size_t)(bm + j * 8 + g_row8) * 512 + k0 + g_ck * 8;
      __builtin_amdgcn_global_load_lds(
          (const __attribute__((address_space(1))) unsigned int*)g,
          (__attribute__((address_space(3))) unsigned int*)(&As[j * 512 + l * 8]),
          16, 0, 0);
    }
    if (!fmode) {
      int row = bn + wv * 8 + g_row8;
      const unsigned short* g = (const unsigned short*)Bw + (size_t)row * 512 + k0 + g_ck * 8;
      __builtin_amdgcn_global_load_lds(
          (const __attribute__((address_space(1))) unsigned int*)g,
          (__attribute__((address_space(3))) unsigned int*)(&Bs[wv * 512 + l * 8]),
          16, 0, 0);
    } else {
      int row = t >> 3, cb = t & 7;     // 32 rows x 8 chunks
      const float* g = (const float*)Bw + (size_t)(bn + row) * 512 + k0 + cb * 8;
      unsigned int tb[4];
#pragma unroll
      for (int u = 0; u < 4; u++) tb[u] = cvtpk(g[2 * u], g[2 * u + 1]);
      int pc = cb ^ (row & 7);
      *(uint4*)&Bs[row * 64 + pc * 8] = *(const uint4*)tb;
    }
    __syncthreads();
#pragma unroll
    for (int kk = 0; kk < 64; kk += 32) {
      int c = (kk >> 3) + qd;
      short8 af = *(const short8*)&As[(wv * 16 + ln) * 64 + ((c ^ (ln & 7)) * 8)];
#pragma unroll
      for (int tj = 0; tj < 2; tj++) {
        short8 bf = *(const short8*)&Bs[(tj * 16 + ln) * 64 + ((c ^ (ln & 7)) * 8)];
        acc[tj] = __builtin_amdgcn_mfma_f32_16x16x32_bf16(af, bf, acc[tj], 0, 0, 0);
      }
    }
    __syncthreads();
  }
#pragma unroll
  for (int tj = 0; tj < 2; tj++) {
    int col = bn + tj * 16 + ln;
    float bv = biasf[col];
#pragma unroll
    for (int i = 0; i < 4; i++) {
      int row = bm + wv * 16 + qd * 4 + i;
      float v = acc[tj][i] + bv;
      if (fmode) ((float*)C)[(size_t)row * 512 + col] = v;
      else       ((unsigned short*)C)[(size_t)row * 512 + col] = f2bf(v);
    }
  }
}

extern "C" void kernel_launch(void* const* d_in, const int* in_sizes, int n_in,
                              void* d_out, int out_size, void* d_ws, size_t ws_size,
                              hipStream_t stream) {
  unsigned char* ws = (unsigned char*)d_ws;
  // 0:x 1:assignment 2:mask 3:q_w 4:kv_w 5:rel_bias 6:proj_w 7:proj_b
  // dtype dispatch at capture time: x f32 = 16*128*512*4 bytes
  const bool f32in = (in_sizes[0] >= 16 * 128 * 512 * 4);
  k_phase1<<<896, 256, 0, stream>>>(d_in[0], d_in[3], d_in[4], d_in[1],
                                    (const unsigned char*)d_in[2],
                                    d_in[5], d_in[7], d_in[6], ws, d_out);
  if (f32in) {
    k_attn_f32<<<256, 512, 0, stream>>>(
        (const unsigned short*)(ws + OFF_XQ),
        (const unsigned short*)(ws + OFF_VT),
        (const unsigned short*)(ws + OFF_AT),
        (const unsigned int*)(ws + OFF_MB),
        (const float*)(ws + OFF_RBF),
        (const unsigned short*)(ws + OFF_PW),
        (float*)d_out);
  } else {
    k_attn_bf16<<<1024, 512, 0, stream>>>(
        (const unsigned short*)(ws + OFF_XQ),
        (const unsigned short*)(ws + OFF_VT),
        (const unsigned short*)(ws + OFF_AT),
        (const unsigned int*)(ws + OFF_MB),
        (const float*)(ws + OFF_RBF),
        (unsigned short*)(ws + OFF_ATTO));
    k_proj<<<dim3(32, 16), 256, 0, stream>>>(
        (const unsigned short*)(ws + OFF_ATTO), d_in[6],
        (const float*)(ws + OFF_PBF), (const int*)ws, d_out);
  }
}